// Round 9
// baseline (678.853 us; speedup 1.0000x reference)
//
#include <hip/hip_runtime.h>
#include <hip/hip_bf16.h>
#include <hip/hip_fp16.h>
#include <stdint.h>

typedef __hip_bfloat16 bf16;

__device__ __forceinline__ float us2f(uint16_t u){
  union { uint32_t i; float f; } v; v.i = ((uint32_t)u) << 16; return v.f;
}
__device__ __forceinline__ float bflo(uint32_t u){
  union { uint32_t i; float f; } v; v.i = u << 16; return v.f;
}
__device__ __forceinline__ float bfhi(uint32_t u){
  union { uint32_t i; float f; } v; v.i = u & 0xffff0000u; return v.f;
}
__device__ __forceinline__ uint16_t f2u16(float f){
  union { bf16 b; uint16_t u; } v; v.b = __float2bfloat16(f); return v.u;
}
// fp16 storage type (distinct from uint16_t=bf16 for overload resolution)
struct h16 { uint16_t v; };

// storage helpers: h buffers are float, bf16(uint16_t), or fp16(h16)
__device__ __forceinline__ float  ldh (const float* p, size_t i){ return p[i]; }
__device__ __forceinline__ float  ldh (const uint16_t* p, size_t i){ return us2f(p[i]); }
__device__ __forceinline__ float  ldh (const h16* p, size_t i){ return __half2float(((const __half*)p)[i]); }
__device__ __forceinline__ float2 ldh2(const float* p, size_t i){ return ((const float2*)p)[i]; }
__device__ __forceinline__ float2 ldh2(const uint16_t* p, size_t i){
  uint32_t u = ((const uint32_t*)p)[i]; return make_float2(bflo(u), bfhi(u));
}
__device__ __forceinline__ float2 ldh2(const h16* p, size_t i){
  __half2 u = ((const __half2*)p)[i];
  return make_float2(__low2float(u), __high2float(u));
}
__device__ __forceinline__ void sth (float* p, size_t i, float v){ p[i] = v; }
__device__ __forceinline__ void sth (uint16_t* p, size_t i, float v){ p[i] = f2u16(v); }
__device__ __forceinline__ void sth (h16* p, size_t i, float v){ ((__half*)p)[i] = __float2half(v); }
__device__ __forceinline__ void sth2(float* p, size_t i, float2 v){ ((float2*)p)[i] = v; }
__device__ __forceinline__ void sth2(uint16_t* p, size_t i, float2 v){
  ((uint32_t*)p)[i] = (uint32_t)f2u16(v.x) | ((uint32_t)f2u16(v.y) << 16);
}
__device__ __forceinline__ void sth2(h16* p, size_t i, float2 v){
  ((__half2*)p)[i] = __float22half2_rn(v);
}
// 4-wide loaders/stores for the aggregate gather (index i4: 4-elem units)
__device__ __forceinline__ void ld4(const float* p, size_t i4, float* o){
  float4 v = ((const float4*)p)[i4]; o[0]=v.x; o[1]=v.y; o[2]=v.z; o[3]=v.w;
}
__device__ __forceinline__ void ld4(const uint16_t* p, size_t i4, float* o){
  uint2 u = ((const uint2*)p)[i4];
  o[0]=bflo(u.x); o[1]=bfhi(u.x); o[2]=bflo(u.y); o[3]=bfhi(u.y);
}
__device__ __forceinline__ void ld4(const h16* p, size_t i4, float* o){
  __half2 u0 = ((const __half2*)p)[i4*2];
  __half2 u1 = ((const __half2*)p)[i4*2+1];
  o[0]=__low2float(u0); o[1]=__high2float(u0);
  o[2]=__low2float(u1); o[3]=__high2float(u1);
}
__device__ __forceinline__ void ld2v(const float* p, size_t i2, float* o){
  float2 v = ((const float2*)p)[i2]; o[0]=v.x; o[1]=v.y;
}
__device__ __forceinline__ void ld2v(const uint16_t* p, size_t i2, float* o){
  uint32_t u = ((const uint32_t*)p)[i2]; o[0]=bflo(u); o[1]=bfhi(u);
}
__device__ __forceinline__ void ld2v(const h16* p, size_t i2, float* o){
  __half2 u = ((const __half2*)p)[i2]; o[0]=__low2float(u); o[1]=__high2float(u);
}
__device__ __forceinline__ void st4(float* p, size_t i4, const float* o){
  ((float4*)p)[i4] = make_float4(o[0],o[1],o[2],o[3]);
}
__device__ __forceinline__ void st4(uint16_t* p, size_t i4, const float* o){
  uint2 u;
  u.x = (uint32_t)f2u16(o[0]) | ((uint32_t)f2u16(o[1]) << 16);
  u.y = (uint32_t)f2u16(o[2]) | ((uint32_t)f2u16(o[3]) << 16);
  ((uint2*)p)[i4] = u;
}
__device__ __forceinline__ void st4(h16* p, size_t i4, const float* o){
  ((__half2*)p)[i4*2]   = __float22half2_rn(make_float2(o[0],o[1]));
  ((__half2*)p)[i4*2+1] = __float22half2_rn(make_float2(o[2],o[3]));
}

// ---------------- x-dtype detection (fp32 vs bf16) — safety net ----------------
__global__ void detect_kernel(const uint32_t* __restrict__ x, int* __restrict__ flag){
  int lane = threadIdx.x;
  uint32_t w = x[lane];
  uint32_t e = (w >> 7) & 0xffu;
  bool looks_bf16 = (e >= 118 && e <= 134);
  unsigned long long m = __ballot(looks_bf16);
  if (lane == 0) flag[0] = (__popcll(m) >= 32) ? 0 : 1;   // 1 = fp32 inputs
}

// ---------------- edge-dtype detection (int32 vs int64) — safety net ----------
__global__ void edetect_kernel(const uint32_t* __restrict__ ei, int* __restrict__ eflag){
  int lane = threadIdx.x;   // 64
  uint32_t w = ei[lane];
  bool ok = (lane & 1) ? (w == 0u) : true;
  unsigned long long m = __ballot(ok);
  if (lane == 0) eflag[0] = (__popcll(m) == 64) ? 1 : 0;  // 1 = int64 edges
}

// ---------------- params -> canonical fp32 copies ----------------
struct PP {
  const void* src[14];
  int off[14];
  int cnt[14];
};

__global__ void cvt_params_kernel(PP pp, float* __restrict__ dst, const int* __restrict__ flag){
  int b = blockIdx.x;
  int cnt = pp.cnt[b];
  float* d = dst + pp.off[b];
  if (flag[0] != 0){
    const float* s = (const float*)pp.src[b];
    for (int i = threadIdx.x; i < cnt; i += 256) d[i] = s[i];
  } else {
    const uint16_t* s = (const uint16_t*)pp.src[b];
    for (int i = threadIdx.x; i < cnt; i += 256) d[i] = us2f(s[i]);
  }
}

// ---------------- CSR build ----------------
// v5 rank trick: the ONLY atomic pass. rank[i] = old count (coalesced write);
// fill then needs no atomic at all (2E -> E device-scope atomics total).
__global__ void count_kernel(const int* __restrict__ ei, const int* __restrict__ eflag,
                             int* __restrict__ counts, int* __restrict__ rank,
                             int E, int n){
  int i = blockIdx.x * 256 + threadIdx.x;
  if (i >= E + n) return;
  int d;
  if (i < E) d = eflag[0] ? ei[2*(size_t)E + 2*(size_t)i] : ei[(size_t)E + i];
  else       d = i - E;
  rank[i] = atomicAdd(&counts[d], 1);
}

#define SCAN_BS 256
#define SCAN_CHUNK 1024

__global__ void scan1_kernel(const int* __restrict__ counts, int* __restrict__ offs,
                             int* __restrict__ bsums, int n){
  __shared__ int sdata[SCAN_BS];
  int b = blockIdx.x, t = threadIdx.x;
  int base = b * SCAN_CHUNK + t * 4;
  int v[4]; int s = 0;
  #pragma unroll
  for (int j=0;j<4;j++){ int idx = base+j; v[j] = (idx<n)? counts[idx] : 0; s += v[j]; }
  sdata[t] = s;
  __syncthreads();
  for (int off=1; off<SCAN_BS; off<<=1){
    int x = (t>=off)? sdata[t-off] : 0;
    __syncthreads();
    sdata[t] += x;
    __syncthreads();
  }
  int run = sdata[t] - s;
  #pragma unroll
  for (int j=0;j<4;j++){ int idx = base+j; if (idx<n) offs[idx] = run; run += v[j]; }
  if (t == SCAN_BS-1) bsums[b] = sdata[t];
}

__global__ void scan2_kernel(int* __restrict__ bsums, int nb){
  __shared__ int sdata[1024];
  int t = threadIdx.x;
  int v = (t<nb)? bsums[t] : 0;
  sdata[t] = v;
  __syncthreads();
  for (int off=1; off<1024; off<<=1){
    int x = (t>=off)? sdata[t-off] : 0;
    __syncthreads();
    sdata[t] += x;
    __syncthreads();
  }
  if (t<nb) bsums[t] = sdata[t] - v;
}

__global__ void scan3_kernel(int* __restrict__ offs, const int* __restrict__ bsums,
                             int n, int total){
  int i = blockIdx.x * 256 + threadIdx.x;
  if (i < n) offs[i] += bsums[i / SCAN_CHUNK];
  if (i == n) offs[n] = total;
}

// atomic-free fill: coalesced ei+rank reads, L2-resident offs gather, scatter store
__global__ void fill_kernel(const int* __restrict__ ei, const int* __restrict__ eflag,
                            const int* __restrict__ offs, const int* __restrict__ rank,
                            int* __restrict__ csr, int E, int n){
  int i = blockIdx.x * 256 + threadIdx.x;
  if (i >= E + n) return;
  int s, d;
  if (i < E){
    if (eflag[0]){ s = ei[2*(size_t)i]; d = ei[2*(size_t)E + 2*(size_t)i]; }
    else         { s = ei[i];           d = ei[(size_t)E + i]; }
  } else { s = i - E; d = i - E; }
  csr[offs[d] + rank[i]] = s;
}

// ---- GEMM v4: C[n,M] = A[n,K] @ W[K,M], LDS-staged, conflict-free ----
// vs v3: register tile doubled to RT x 8 (M=128: 8x8, 64 acc) with BR=128.
// Halves DS-read intensity (0.25 reads/FMA vs 0.375) and halves wave count
// -> DS-pipe floor ~17us (was ~31us, the R8 tallest pole). Strided col
// ownership (tx + TX*j) keeps all LDS reads conflict-free broadcasts.
template<int K, int M, bool DET, typename TA, typename TC>
__global__ __launch_bounds__(256) void gemm_kernel(const void* __restrict__ Ap,
    const float* __restrict__ W, TC* __restrict__ C, int n, const int* __restrict__ flag){
  constexpr int TX = M/8;          // 128->16, 64->8
  constexpr int BR = 128;          // rows per block
  constexpr int RT = (BR*M)/2048;  // rows per thread: 128->8, 64->4
  constexpr int KC = K/32;
  __shared__ float As[BR*33];      // 16.9 KB
  __shared__ float Ws[32*M];       // M=128: 16.4 KB
  int tid = threadIdx.x;
  int tx = tid % TX;               // cols tx + TX*j, j=0..7 (strided)
  int ty = tid / TX;               // row group: rows ty*RT .. ty*RT+RT-1
  int r0b = blockIdx.x * BR;

  bool f32 = DET ? (flag[0] != 0) : false;
  const uint16_t* Au = (const uint16_t*)Ap;
  const float*    Af = (const float*)Ap;
  const TA*       At = (const TA*)Ap;

  float acc[RT][8];
  #pragma unroll
  for (int r=0;r<RT;r++)
    #pragma unroll
    for (int j=0;j<8;j++) acc[r][j] = 0.f;

  for (int c=0; c<KC; c++){
    // stage W chunk (32 x M), coalesced float4, dense row-major
    const float4* Wg = (const float4*)(W + (size_t)c*32*M);
    for (int i=tid; i < 32*M/4; i += 256) ((float4*)Ws)[i] = Wg[i];
    // stage A chunk (BR x 32), coalesced within rows, padded stride 33
    for (int i=tid; i < BR*32; i += 256){
      int r = i >> 5, k = i & 31;
      int gr = r0b + r;
      float a = 0.f;
      if (gr < n){
        size_t idx = (size_t)gr*K + c*32 + k;
        if (DET) a = f32 ? Af[idx] : us2f(Au[idx]);
        else     a = ldh(At, idx);
      }
      As[r*33 + k] = a;
    }
    __syncthreads();
    #pragma unroll 4
    for (int k2=0; k2<32; k2++){
      float a[RT];
      #pragma unroll
      for (int r=0;r<RT;r++) a[r] = As[(ty*RT+r)*33 + k2];
      float w[8];
      #pragma unroll
      for (int j=0;j<8;j++) w[j] = Ws[k2*M + tx + TX*j];
      #pragma unroll
      for (int r=0;r<RT;r++)
        #pragma unroll
        for (int j=0;j<8;j++)
          acc[r][j] = fmaf(a[r], w[j], acc[r][j]);
    }
    __syncthreads();
  }
  #pragma unroll
  for (int r=0;r<RT;r++){
    int gr = r0b + ty*RT + r;
    if (gr < n){
      #pragma unroll
      for (int j=0;j<8;j++)
        sth(C, (size_t)gr*M + tx + TX*j, acc[r][j]);
    }
  }
}

// ---------------- per-node attention logits ----------------
template<int OUTD, int HD, typename T>
__global__ void logits_kernel(const T* __restrict__ hW, const float* __restrict__ a_src,
                              const float* __restrict__ a_dst, float* __restrict__ als,
                              float* __restrict__ ald, int n){
  int i = blockIdx.x * 256 + threadIdx.x;   // i = node*4 + h
  if (i >= n*4) return;
  int node = i >> 2, h = i & 3;
  const T* hp = hW + (size_t)node*OUTD + h*HD;
  float ss = 0.f, sd = 0.f;
  #pragma unroll
  for (int d2=0; d2<HD/2; d2++){
    float2 v = ldh2(hp, d2);
    int b = h*HD + 2*d2;
    ss += v.x*a_src[b] + v.y*a_src[b+1];
    sd += v.x*a_dst[b] + v.y*a_dst[b+1];
  }
  als[i] = ss; ald[i] = sd;
}

// ---------------- aggregation: one wave per destination node ----------------
// v4: SINGLE PASS — segment-max removed (softmax is shift-invariant; logits
// here are |e| <~ 10 << 88, exp(e) cannot overflow fp32). Fully predicated:
// 4 row-gathers per half-wave every iteration, OOB slots clamp with ex=0.
template<int OUTD, typename TIN, typename TOUT>
__global__ __launch_bounds__(256) void aggregate_kernel(const TIN* __restrict__ hW,
            const float* __restrict__ als, const float* __restrict__ ald,
            const int* __restrict__ offs, const int* __restrict__ csr,
            const float* __restrict__ bias, TOUT* __restrict__ hout, int n){
  constexpr int VEC = OUTD / 32;          // 4 (OUTD=128) or 2 (OUTD=64)
  int wid = (blockIdx.x * 256 + threadIdx.x) >> 6;   // node
  if (wid >= n) return;
  int lane = threadIdx.x & 63;
  int half = lane >> 5;
  int l2   = lane & 31;
  int h    = l2 >> 3;       // head for this lane's dims (both OUTD)
  int beg = offs[wid], end = offs[wid+1];
  float adh = ald[(size_t)wid*4 + h];

  float acc[VEC];
  #pragma unroll
  for (int k=0;k<VEC;k++) acc[k] = 0.f;
  float den = 0.f;

  int last = end - 1;
  for (int j = beg + half; j < end; j += 8){
    int j1 = j+2, j2 = j+4, j3 = j+6;
    bool p1 = j1 < end, p2 = j2 < end, p3 = j3 < end;
    int s0 = csr[j];
    int s1 = csr[p1 ? j1 : last];
    int s2 = csr[p2 ? j2 : last];
    int s3 = csr[p3 ? j3 : last];
    float v0[VEC], v1[VEC], v2[VEC], v3[VEC];
    if constexpr (VEC == 4){
      ld4(hW, (size_t)s0*32 + l2, v0);
      ld4(hW, (size_t)s1*32 + l2, v1);
      ld4(hW, (size_t)s2*32 + l2, v2);
      ld4(hW, (size_t)s3*32 + l2, v3);
    } else {
      ld2v(hW, (size_t)s0*32 + l2, v0);
      ld2v(hW, (size_t)s1*32 + l2, v1);
      ld2v(hW, (size_t)s2*32 + l2, v2);
      ld2v(hW, (size_t)s3*32 + l2, v3);
    }
    float e0 = als[(size_t)s0*4 + h] + adh;
    float e1 = als[(size_t)s1*4 + h] + adh;
    float e2 = als[(size_t)s2*4 + h] + adh;
    float e3 = als[(size_t)s3*4 + h] + adh;
    e0 = (e0>0.f)? e0 : 0.2f*e0;
    e1 = (e1>0.f)? e1 : 0.2f*e1;
    e2 = (e2>0.f)? e2 : 0.2f*e2;
    e3 = (e3>0.f)? e3 : 0.2f*e3;
    float ex0 = __expf(e0);
    float ex1 = p1 ? __expf(e1) : 0.f;
    float ex2 = p2 ? __expf(e2) : 0.f;
    float ex3 = p3 ? __expf(e3) : 0.f;
    den += (ex0 + ex1) + (ex2 + ex3);
    #pragma unroll
    for (int k=0;k<VEC;k++){
      acc[k] = fmaf(ex0, v0[k], acc[k]);
      acc[k] = fmaf(ex1, v1[k], acc[k]);
      acc[k] = fmaf(ex2, v2[k], acc[k]);
      acc[k] = fmaf(ex3, v3[k], acc[k]);
    }
  }

  // combine the two halves
  den += __shfl_xor(den, 32);
  #pragma unroll
  for (int k=0;k<VEC;k++) acc[k] += __shfl_xor(acc[k], 32);

  if (half == 0){
    float inv = 1.f / (den + 1e-16f);
    float o[VEC];
    if constexpr (VEC == 4){
      const float4 bv = ((const float4*)bias)[l2];
      o[0] = fmaf(acc[0], inv, bv.x);
      o[1] = fmaf(acc[1], inv, bv.y);
      o[2] = fmaf(acc[2], inv, bv.z);
      o[3] = fmaf(acc[3], inv, bv.w);
      #pragma unroll
      for (int k=0;k<4;k++) o[k] = (o[k]>0.f)? o[k] : 0.f;
      st4(hout, (size_t)wid*32 + l2, o);
    } else {
      const float2 bv = ((const float2*)bias)[l2];
      o[0] = fmaf(acc[0], inv, bv.x);
      o[1] = fmaf(acc[1], inv, bv.y);
      o[0] = (o[0]>0.f)? o[0] : 0.f;
      o[1] = (o[1]>0.f)? o[1] : 0.f;
      sth2(hout, (size_t)wid*32 + l2, make_float2(o[0], o[1]));
    }
  }
}

// ---------- classifier v3: out[n,40] = h[n,64] @ Wc + bc (fp32 output) -------
// Structural clone of gemm_kernel (proven): row-major As[128][65] staged with
// the same coalesced copy loop; Ws[64][40] dense; thread = 4 rows x 5 cols;
// scalar broadcast LDS reads in k-loop. No shuffles, no transposed staging.
template<typename T>
__global__ __launch_bounds__(256) void classifier_kernel(const T* __restrict__ h,
      const float* __restrict__ Wc, const float* __restrict__ bc,
      float* __restrict__ out, int n){
  __shared__ float As[128*65];    // 33.3 KB
  __shared__ float Ws[64*40];     // 10.24 KB
  __shared__ float bs[40];
  int t = threadIdx.x;
  int r0b = blockIdx.x * 128;

  // stage Wc (2560 floats) + bias
  for (int i=t; i<2560; i+=256) Ws[i] = Wc[i];
  if (t < 40) bs[t] = bc[t];

  // stage h tile (128 rows x 64), coalesced within rows, padded stride 65
  for (int i=t; i < 128*64; i += 256){
    int r = i >> 6, k = i & 63;
    int gr = r0b + r;
    float a = 0.f;
    if (gr < n) a = ldh(h, (size_t)gr*64 + k);
    As[r*65 + k] = a;
  }
  __syncthreads();

  int tx = t & 7;        // cols tx*5 .. tx*5+4
  int ty = t >> 3;       // rows ty*4 .. ty*4+3
  float acc[4][5];
  #pragma unroll
  for (int r=0;r<4;r++)
    #pragma unroll
    for (int c=0;c<5;c++) acc[r][c] = 0.f;

  #pragma unroll 8
  for (int k=0; k<64; k++){
    float a0 = As[(ty*4+0)*65 + k];
    float a1 = As[(ty*4+1)*65 + k];
    float a2 = As[(ty*4+2)*65 + k];
    float a3 = As[(ty*4+3)*65 + k];
    float w[5];
    #pragma unroll
    for (int c=0;c<5;c++) w[c] = Ws[k*40 + tx*5 + c];
    #pragma unroll
    for (int c=0;c<5;c++){
      acc[0][c] = fmaf(a0, w[c], acc[0][c]);
      acc[1][c] = fmaf(a1, w[c], acc[1][c]);
      acc[2][c] = fmaf(a2, w[c], acc[2][c]);
      acc[3][c] = fmaf(a3, w[c], acc[3][c]);
    }
  }

  #pragma unroll
  for (int r=0;r<4;r++){
    int gr = r0b + ty*4 + r;
    if (gr < n){
      #pragma unroll
      for (int c=0;c<5;c++)
        out[(size_t)gr*40 + tx*5 + c] = acc[r][c] + bs[tx*5 + c];
    }
  }
}

// ---------------- pipeline ----------------
template<typename TM, typename TO>
static void run_pipeline(void* const* d_in, int ei_idx, int pbase, int n, int E,
                         void* d_out, int out_size, void* d_ws, size_t ws_size,
                         hipStream_t stream){
  const void* x = d_in[0];
  const int* ei = (const int*)d_in[ei_idx];
  float* out = (float*)d_out;           // fp32 output (R8 sentinel evidence)
  int Etot = E + n;

  char* p = (char*)d_ws;
  auto alloc = [&](size_t bytes)->char* {
    char* r = p; p += (bytes + 255) & ~(size_t)255; return r;
  };
  int*   flag   = (int*)  alloc(256);
  int*   eflag  = (int*)  alloc(256);
  int*   counts = (int*)  alloc((size_t)n * 4);
  float* als    = (float*)alloc((size_t)n * 16);
  float* ald    = (float*)alloc((size_t)n * 16);
  float* prm    = (float*)alloc(48000 * 4);

  // csr/offs/rank/bsums in d_out (fp32 out: 16 MB; dead until classifier)
  size_t csr_b  = ((size_t)Etot * 4 + 255) & ~(size_t)255;
  size_t offs_b = ((size_t)(n + 1) * 4 + 255) & ~(size_t)255;
  size_t rank_b = ((size_t)Etot * 4 + 255) & ~(size_t)255;
  size_t out_bytes = (size_t)out_size * 4;
  int *csr, *offs, *rank, *bsums;
  if (csr_b + offs_b + rank_b + 4096 <= out_bytes){
    char* q = (char*)d_out;
    csr   = (int*)q;
    offs  = (int*)(q + csr_b);
    rank  = (int*)(q + csr_b + offs_b);
    bsums = (int*)(q + csr_b + offs_b + rank_b);
  } else {
    csr   = (int*)alloc((size_t)Etot * 4);
    offs  = (int*)alloc((size_t)(n + 1) * 4);
    rank  = (int*)alloc((size_t)Etot * 4);
    bsums = (int*)alloc(4096);
  }
  TM* bufMid = (TM*)alloc((size_t)n * 128 * sizeof(TM));
  TO* bufOut = (TO*)alloc((size_t)n * 128 * sizeof(TO));

  PP pp;
  static const int cnts[14] = {16384,128,128,128, 16384,128,128,128, 8192,64,64,64, 2560,40};
  int off = 0;
  for (int i = 0; i < 14; i++){
    pp.src[i] = d_in[pbase + i];
    pp.cnt[i] = cnts[i];
    pp.off[i] = off;
    off += cnts[i];
  }
  const float* W0  = prm + pp.off[0];
  const float* as0 = prm + pp.off[1];
  const float* ad0 = prm + pp.off[2];
  const float* b0  = prm + pp.off[3];
  const float* W1  = prm + pp.off[4];
  const float* as1 = prm + pp.off[5];
  const float* ad1 = prm + pp.off[6];
  const float* b1  = prm + pp.off[7];
  const float* W2  = prm + pp.off[8];
  const float* as2 = prm + pp.off[9];
  const float* ad2 = prm + pp.off[10];
  const float* b2  = prm + pp.off[11];
  const float* Wc  = prm + pp.off[12];
  const float* bc  = prm + pp.off[13];

  hipMemsetAsync(counts, 0, (size_t)n * 4, stream);

  detect_kernel<<<1, 64, 0, stream>>>((const uint32_t*)x, flag);
  edetect_kernel<<<1, 64, 0, stream>>>((const uint32_t*)ei, eflag);
  cvt_params_kernel<<<14, 256, 0, stream>>>(pp, prm, flag);

  count_kernel<<<(Etot + 255)/256, 256, 0, stream>>>(ei, eflag, counts, rank, E, n);
  int nb = (n + SCAN_CHUNK - 1) / SCAN_CHUNK;
  scan1_kernel<<<nb, SCAN_BS, 0, stream>>>(counts, offs, bsums, n);
  scan2_kernel<<<1, 1024, 0, stream>>>(bsums, nb);
  scan3_kernel<<<(n + 1 + 255)/256, 256, 0, stream>>>(offs, bsums, n, Etot);
  fill_kernel<<<(Etot + 255)/256, 256, 0, stream>>>(ei, eflag, offs, rank, csr, E, n);

  int gg   = (n + 127) / 128;    // gemm v4: BR=128 both M
  int log_grid = (n*4 + 255) / 256;
  int agg_grid = (n + 3) / 4;
  int cls_grid = (n + 127) / 128;

  // layer 0: x -> bufMid -> bufOut   (x dtype runtime-detected; expect fp32)
  gemm_kernel<128,128,true,TO,TM><<<gg, 256, 0, stream>>>(x, W0, bufMid, n, flag);
  logits_kernel<128,32,TM><<<log_grid, 256, 0, stream>>>(bufMid, as0, ad0, als, ald, n);
  aggregate_kernel<128,TM,TO><<<agg_grid, 256, 0, stream>>>(bufMid, als, ald, offs, csr, b0, bufOut, n);

  // layer 1
  gemm_kernel<128,128,false,TO,TM><<<gg, 256, 0, stream>>>(bufOut, W1, bufMid, n, flag);
  logits_kernel<128,32,TM><<<log_grid, 256, 0, stream>>>(bufMid, as1, ad1, als, ald, n);
  aggregate_kernel<128,TM,TO><<<agg_grid, 256, 0, stream>>>(bufMid, als, ald, offs, csr, b1, bufOut, n);

  // layer 2 (outd=64)
  gemm_kernel<128,64,false,TO,TM><<<gg, 256, 0, stream>>>(bufOut, W2, bufMid, n, flag);
  logits_kernel<64,16,TM><<<log_grid, 256, 0, stream>>>(bufMid, as2, ad2, als, ald, n);
  aggregate_kernel<64,TM,TO><<<agg_grid, 256, 0, stream>>>(bufMid, als, ald, offs, csr, b2, bufOut, n);

  // classifier: fp32 writes, fully overwrites d_out
  classifier_kernel<TO><<<cls_grid, 256, 0, stream>>>(bufOut, Wc, bc, out, n);
}

// ---------------- launcher ----------------
extern "C" void kernel_launch(void* const* d_in, const int* in_sizes, int n_in,
                              void* d_out, int out_size, void* d_ws, size_t ws_size,
                              hipStream_t stream) {
  int n = in_sizes[0] / 128;

  int ei_idx, pbase;
  if (n_in >= 2 && in_sizes[1] > 1000000) { ei_idx = 1;        pbase = 2; }   // dict order
  else                                    { ei_idx = n_in - 1; pbase = 1; }   // signature order
  int E = in_sizes[ei_idx] / 2;

  size_t base = 512
              + (((size_t)n*4  + 255) & ~(size_t)255)
              + 2*(((size_t)n*16 + 255) & ~(size_t)255)
              + ((48000*4 + 255) & ~(size_t)255)
              + 65536
              + 3*(((size_t)(E + n)*4 + 255) & ~(size_t)255);  // csr/offs/rank fallback
  size_t f32buf  = ((size_t)n*128*4 + 255) & ~(size_t)255;
  size_t h16buf  = ((size_t)n*128*2 + 255) & ~(size_t)255;

  if (ws_size >= base + f32buf + h16buf)       // tier 1: fp16 gather buf, fp32 h
    run_pipeline<h16, float>(d_in, ei_idx, pbase, n, E, d_out, out_size, d_ws, ws_size, stream);
  else                                         // tier 2: all 16-bit
    run_pipeline<h16, uint16_t>(d_in, ei_idx, pbase, n, E, d_out, out_size, d_ws, ws_size, stream);
}

// Round 10
// 586.063 us; speedup vs baseline: 1.1583x; 1.1583x over previous
//
#include <hip/hip_runtime.h>
#include <hip/hip_bf16.h>
#include <hip/hip_fp16.h>
#include <stdint.h>

typedef __hip_bfloat16 bf16;
typedef _Float16 f16;
typedef __attribute__((ext_vector_type(8))) _Float16 f16x8;
typedef __attribute__((ext_vector_type(4))) float    f32x4;

__device__ __forceinline__ float us2f(uint16_t u){
  union { uint32_t i; float f; } v; v.i = ((uint32_t)u) << 16; return v.f;
}
__device__ __forceinline__ float bflo(uint32_t u){
  union { uint32_t i; float f; } v; v.i = u << 16; return v.f;
}
__device__ __forceinline__ float bfhi(uint32_t u){
  union { uint32_t i; float f; } v; v.i = u & 0xffff0000u; return v.f;
}
__device__ __forceinline__ uint16_t f2u16(float f){
  union { bf16 b; uint16_t u; } v; v.b = __float2bfloat16(f); return v.u;
}
// fp16 storage type (distinct from uint16_t=bf16 for overload resolution)
struct h16 { uint16_t v; };

// storage helpers: h buffers are float, bf16(uint16_t), or fp16(h16)
__device__ __forceinline__ float  ldh (const float* p, size_t i){ return p[i]; }
__device__ __forceinline__ float  ldh (const uint16_t* p, size_t i){ return us2f(p[i]); }
__device__ __forceinline__ float  ldh (const h16* p, size_t i){ return __half2float(((const __half*)p)[i]); }
__device__ __forceinline__ float2 ldh2(const float* p, size_t i){ return ((const float2*)p)[i]; }
__device__ __forceinline__ float2 ldh2(const uint16_t* p, size_t i){
  uint32_t u = ((const uint32_t*)p)[i]; return make_float2(bflo(u), bfhi(u));
}
__device__ __forceinline__ float2 ldh2(const h16* p, size_t i){
  __half2 u = ((const __half2*)p)[i];
  return make_float2(__low2float(u), __high2float(u));
}
__device__ __forceinline__ void sth (float* p, size_t i, float v){ p[i] = v; }
__device__ __forceinline__ void sth (uint16_t* p, size_t i, float v){ p[i] = f2u16(v); }
__device__ __forceinline__ void sth (h16* p, size_t i, float v){ ((__half*)p)[i] = __float2half(v); }
__device__ __forceinline__ void sth2(float* p, size_t i, float2 v){ ((float2*)p)[i] = v; }
__device__ __forceinline__ void sth2(uint16_t* p, size_t i, float2 v){
  ((uint32_t*)p)[i] = (uint32_t)f2u16(v.x) | ((uint32_t)f2u16(v.y) << 16);
}
__device__ __forceinline__ void sth2(h16* p, size_t i, float2 v){
  ((__half2*)p)[i] = __float22half2_rn(v);
}
// 4-wide loaders/stores for the aggregate gather (index i4: 4-elem units)
__device__ __forceinline__ void ld4(const float* p, size_t i4, float* o){
  float4 v = ((const float4*)p)[i4]; o[0]=v.x; o[1]=v.y; o[2]=v.z; o[3]=v.w;
}
__device__ __forceinline__ void ld4(const uint16_t* p, size_t i4, float* o){
  uint2 u = ((const uint2*)p)[i4];
  o[0]=bflo(u.x); o[1]=bfhi(u.x); o[2]=bflo(u.y); o[3]=bfhi(u.y);
}
__device__ __forceinline__ void ld4(const h16* p, size_t i4, float* o){
  __half2 u0 = ((const __half2*)p)[i4*2];
  __half2 u1 = ((const __half2*)p)[i4*2+1];
  o[0]=__low2float(u0); o[1]=__high2float(u0);
  o[2]=__low2float(u1); o[3]=__high2float(u1);
}
__device__ __forceinline__ void ld2v(const float* p, size_t i2, float* o){
  float2 v = ((const float2*)p)[i2]; o[0]=v.x; o[1]=v.y;
}
__device__ __forceinline__ void ld2v(const uint16_t* p, size_t i2, float* o){
  uint32_t u = ((const uint32_t*)p)[i2]; o[0]=bflo(u); o[1]=bfhi(u);
}
__device__ __forceinline__ void ld2v(const h16* p, size_t i2, float* o){
  __half2 u = ((const __half2*)p)[i2]; o[0]=__low2float(u); o[1]=__high2float(u);
}
__device__ __forceinline__ void st4(float* p, size_t i4, const float* o){
  ((float4*)p)[i4] = make_float4(o[0],o[1],o[2],o[3]);
}
__device__ __forceinline__ void st4(uint16_t* p, size_t i4, const float* o){
  uint2 u;
  u.x = (uint32_t)f2u16(o[0]) | ((uint32_t)f2u16(o[1]) << 16);
  u.y = (uint32_t)f2u16(o[2]) | ((uint32_t)f2u16(o[3]) << 16);
  ((uint2*)p)[i4] = u;
}
__device__ __forceinline__ void st4(h16* p, size_t i4, const float* o){
  ((__half2*)p)[i4*2]   = __float22half2_rn(make_float2(o[0],o[1]));
  ((__half2*)p)[i4*2+1] = __float22half2_rn(make_float2(o[2],o[3]));
}
// 8-wide consecutive loaders (32B-aligned base), for MFMA A-frags
__device__ __forceinline__ void ld8(const float* p, size_t i, float* o){
  float4 a = ((const float4*)(p+i))[0];
  float4 b = ((const float4*)(p+i))[1];
  o[0]=a.x; o[1]=a.y; o[2]=a.z; o[3]=a.w; o[4]=b.x; o[5]=b.y; o[6]=b.z; o[7]=b.w;
}
__device__ __forceinline__ void ld8(const uint16_t* p, size_t i, float* o){
  uint4 u = *(const uint4*)(p+i);
  o[0]=bflo(u.x); o[1]=bfhi(u.x); o[2]=bflo(u.y); o[3]=bfhi(u.y);
  o[4]=bflo(u.z); o[5]=bfhi(u.z); o[6]=bflo(u.w); o[7]=bfhi(u.w);
}
__device__ __forceinline__ void ld8(const h16* p, size_t i, float* o){
  const __half2* q = (const __half2*)(p+i);
  #pragma unroll
  for (int j=0;j<4;j++){ __half2 u=q[j]; o[2*j]=__low2float(u); o[2*j+1]=__high2float(u); }
}

// ---------------- x-dtype detection (fp32 vs bf16) — safety net ----------------
__global__ void detect_kernel(const uint32_t* __restrict__ x, int* __restrict__ flag){
  int lane = threadIdx.x;
  uint32_t w = x[lane];
  uint32_t e = (w >> 7) & 0xffu;
  bool looks_bf16 = (e >= 118 && e <= 134);
  unsigned long long m = __ballot(looks_bf16);
  if (lane == 0) flag[0] = (__popcll(m) >= 32) ? 0 : 1;   // 1 = fp32 inputs
}

// ---------------- edge-dtype detection (int32 vs int64) — safety net ----------
__global__ void edetect_kernel(const uint32_t* __restrict__ ei, int* __restrict__ eflag){
  int lane = threadIdx.x;   // 64
  uint32_t w = ei[lane];
  bool ok = (lane & 1) ? (w == 0u) : true;
  unsigned long long m = __ballot(ok);
  if (lane == 0) eflag[0] = (__popcll(m) == 64) ? 1 : 0;  // 1 = int64 edges
}

// ---------------- params -> canonical fp32 copies ----------------
struct PP {
  const void* src[14];
  int off[14];
  int cnt[14];
};

__global__ void cvt_params_kernel(PP pp, float* __restrict__ dst, const int* __restrict__ flag){
  int b = blockIdx.x;
  int cnt = pp.cnt[b];
  float* d = dst + pp.off[b];
  if (flag[0] != 0){
    const float* s = (const float*)pp.src[b];
    for (int i = threadIdx.x; i < cnt; i += 256) d[i] = s[i];
  } else {
    const uint16_t* s = (const uint16_t*)pp.src[b];
    for (int i = threadIdx.x; i < cnt; i += 256) d[i] = us2f(s[i]);
  }
}

// ---- W -> fragment-major split-fp16 (wh = fp16(W), wl = fp16(W - wh)) ----
// Entry e = (c*CT + ct)*64 + lane; elem i: k = 32c + 8*(lane>>4) + i,
// m = 16ct + (lane&15). B-frag load in GEMM is then one coalesced b128.
__global__ void wfrag_kernel(const float* __restrict__ W, uint16_t* __restrict__ wh,
                             uint16_t* __restrict__ wl, int K, int M){
  int e = blockIdx.x * 256 + threadIdx.x;
  int CT = M >> 4, KC = K >> 5;
  if (e >= KC*CT*64) return;
  int l = e & 63, t = e >> 6;
  int ct = t % CT, c = t / CT;
  int kbase = c*32 + (l>>4)*8;
  int m = ct*16 + (l&15);
  #pragma unroll
  for (int i=0;i<8;i++){
    float w = W[(size_t)(kbase+i)*M + m];
    f16 h = (f16)w;
    f16 r = (f16)(w - (float)h);
    union { f16 f; uint16_t u; } ch, cr; ch.f = h; cr.f = r;
    wh[(size_t)e*8 + i] = ch.u;
    wl[(size_t)e*8 + i] = cr.u;
  }
}

// ---------------- CSR build ----------------
// v5 rank trick: the ONLY atomic pass. rank[i] = old count (coalesced write);
// fill then needs no atomic at all (2E -> E device-scope atomics total).
__global__ void count_kernel(const int* __restrict__ ei, const int* __restrict__ eflag,
                             int* __restrict__ counts, int* __restrict__ rank,
                             int E, int n){
  int i = blockIdx.x * 256 + threadIdx.x;
  if (i >= E + n) return;
  int d;
  if (i < E) d = eflag[0] ? ei[2*(size_t)E + 2*(size_t)i] : ei[(size_t)E + i];
  else       d = i - E;
  rank[i] = atomicAdd(&counts[d], 1);
}

#define SCAN_BS 256
#define SCAN_CHUNK 1024

__global__ void scan1_kernel(const int* __restrict__ counts, int* __restrict__ offs,
                             int* __restrict__ bsums, int n){
  __shared__ int sdata[SCAN_BS];
  int b = blockIdx.x, t = threadIdx.x;
  int base = b * SCAN_CHUNK + t * 4;
  int v[4]; int s = 0;
  #pragma unroll
  for (int j=0;j<4;j++){ int idx = base+j; v[j] = (idx<n)? counts[idx] : 0; s += v[j]; }
  sdata[t] = s;
  __syncthreads();
  for (int off=1; off<SCAN_BS; off<<=1){
    int x = (t>=off)? sdata[t-off] : 0;
    __syncthreads();
    sdata[t] += x;
    __syncthreads();
  }
  int run = sdata[t] - s;
  #pragma unroll
  for (int j=0;j<4;j++){ int idx = base+j; if (idx<n) offs[idx] = run; run += v[j]; }
  if (t == SCAN_BS-1) bsums[b] = sdata[t];
}

__global__ void scan2_kernel(int* __restrict__ bsums, int nb){
  __shared__ int sdata[1024];
  int t = threadIdx.x;
  int v = (t<nb)? bsums[t] : 0;
  sdata[t] = v;
  __syncthreads();
  for (int off=1; off<1024; off<<=1){
    int x = (t>=off)? sdata[t-off] : 0;
    __syncthreads();
    sdata[t] += x;
    __syncthreads();
  }
  if (t<nb) bsums[t] = sdata[t] - v;
}

__global__ void scan3_kernel(int* __restrict__ offs, const int* __restrict__ bsums,
                             int n, int total){
  int i = blockIdx.x * 256 + threadIdx.x;
  if (i < n) offs[i] += bsums[i / SCAN_CHUNK];
  if (i == n) offs[n] = total;
}

// atomic-free fill: coalesced ei+rank reads, L2-resident offs gather, scatter store
__global__ void fill_kernel(const int* __restrict__ ei, const int* __restrict__ eflag,
                            const int* __restrict__ offs, const int* __restrict__ rank,
                            int* __restrict__ csr, int E, int n){
  int i = blockIdx.x * 256 + threadIdx.x;
  if (i >= E + n) return;
  int s, d;
  if (i < E){
    if (eflag[0]){ s = ei[2*(size_t)i]; d = ei[2*(size_t)E + 2*(size_t)i]; }
    else         { s = ei[i];           d = ei[(size_t)E + i]; }
  } else { s = i - E; d = i - E; }
  csr[offs[d] + rank[i]] = s;
}

// ---- GEMM v5: split-fp16 MFMA, barrier-free, LDS-free ----
// C[n,M] = A[n,K] @ W[K,M].  W pre-split/arranged fragment-major (wfrag).
// A loaded per-lane from global (128B row segments), split in-register:
// ah = fp16(a), al = fp16(a - ah). acc += Ah*Wh + Al*Wh + Ah*Wl (3 MFMA),
// residual ~eps^2 -> fp32-grade accuracy. Wave = 32 rows x M cols, block =
// 4 waves = 128 rows. No __syncthreads, no LDS: the barrier-drain stall of
// v2-v4 is structurally gone. C/D layout per m89: col=lane&15,
// row=(lane>>4)*4+reg. A/B use the same k-map, so result is k-map-invariant.
template<int K, int M, bool DET, typename TA, typename TC>
__global__ __launch_bounds__(256) void gemm_mfma(const void* __restrict__ Ap,
    const uint16_t* __restrict__ whb, const uint16_t* __restrict__ wlb,
    TC* __restrict__ C, int n, const int* __restrict__ flag){
  constexpr int CT = M/16;     // col tiles
  constexpr int KC = K/32;     // k chunks
  constexpr int RT = 2;        // row tiles per wave (32 rows)
  int tid = threadIdx.x;
  int wv  = tid >> 6, l = tid & 63;
  int lr  = l & 15, kg = l >> 4;
  int r0  = blockIdx.x*(64*RT) + wv*(16*RT);

  bool f32 = DET ? (flag[0] != 0) : false;
  const uint16_t* Au = (const uint16_t*)Ap;
  const float*    Af = (const float*)Ap;
  const TA*       At = (const TA*)Ap;
  const f16x8* Wh = (const f16x8*)whb;
  const f16x8* Wl = (const f16x8*)wlb;

  f32x4 acc[RT][CT];
  #pragma unroll
  for (int rt=0;rt<RT;rt++)
    #pragma unroll
    for (int ct=0;ct<CT;ct++) acc[rt][ct] = (f32x4){0.f,0.f,0.f,0.f};

  for (int c=0; c<KC; c++){
    f16x8 ah[RT], al[RT];
    #pragma unroll
    for (int rt=0;rt<RT;rt++){
      int arow = r0 + rt*16 + lr;
      if (arow > n-1) arow = n-1;
      size_t idx = (size_t)arow*K + c*32 + kg*8;
      float av[8];
      if (DET){
        if (f32) ld8(Af, idx, av);
        else     ld8(Au, idx, av);
      } else {
        ld8(At, idx, av);
      }
      #pragma unroll
      for (int i=0;i<8;i++){
        f16 h = (f16)av[i];
        ah[rt][i] = h;
        al[rt][i] = (f16)(av[i] - (float)h);
      }
    }
    #pragma unroll
    for (int ct=0;ct<CT;ct++){
      f16x8 bh = Wh[(size_t)(c*CT + ct)*64 + l];
      f16x8 bl = Wl[(size_t)(c*CT + ct)*64 + l];
      #pragma unroll
      for (int rt=0;rt<RT;rt++){
        acc[rt][ct] = __builtin_amdgcn_mfma_f32_16x16x32_f16(ah[rt], bh, acc[rt][ct], 0, 0, 0);
        acc[rt][ct] = __builtin_amdgcn_mfma_f32_16x16x32_f16(al[rt], bh, acc[rt][ct], 0, 0, 0);
        acc[rt][ct] = __builtin_amdgcn_mfma_f32_16x16x32_f16(ah[rt], bl, acc[rt][ct], 0, 0, 0);
      }
    }
  }

  #pragma unroll
  for (int rt=0;rt<RT;rt++){
    #pragma unroll
    for (int r=0;r<4;r++){
      int orow = r0 + rt*16 + kg*4 + r;
      if (orow < n){
        #pragma unroll
        for (int ct=0;ct<CT;ct++)
          sth(C, (size_t)orow*M + ct*16 + lr, acc[rt][ct][r]);
      }
    }
  }
}

// ---------------- per-node attention logits ----------------
template<int OUTD, int HD, typename T>
__global__ void logits_kernel(const T* __restrict__ hW, const float* __restrict__ a_src,
                              const float* __restrict__ a_dst, float* __restrict__ als,
                              float* __restrict__ ald, int n){
  int i = blockIdx.x * 256 + threadIdx.x;   // i = node*4 + h
  if (i >= n*4) return;
  int node = i >> 2, h = i & 3;
  const T* hp = hW + (size_t)node*OUTD + h*HD;
  float ss = 0.f, sd = 0.f;
  #pragma unroll
  for (int d2=0; d2<HD/2; d2++){
    float2 v = ldh2(hp, d2);
    int b = h*HD + 2*d2;
    ss += v.x*a_src[b] + v.y*a_src[b+1];
    sd += v.x*a_dst[b] + v.y*a_dst[b+1];
  }
  als[i] = ss; ald[i] = sd;
}

// ---------------- aggregation: one wave per destination node ----------------
// SINGLE PASS — segment-max removed (softmax shift-invariant; |e| << 88).
// Fully predicated: 4 row-gathers per half-wave every iteration, OOB slots
// clamp to end-1 with ex=0.
template<int OUTD, typename TIN, typename TOUT>
__global__ __launch_bounds__(256) void aggregate_kernel(const TIN* __restrict__ hW,
            const float* __restrict__ als, const float* __restrict__ ald,
            const int* __restrict__ offs, const int* __restrict__ csr,
            const float* __restrict__ bias, TOUT* __restrict__ hout, int n){
  constexpr int VEC = OUTD / 32;          // 4 (OUTD=128) or 2 (OUTD=64)
  int wid = (blockIdx.x * 256 + threadIdx.x) >> 6;   // node
  if (wid >= n) return;
  int lane = threadIdx.x & 63;
  int half = lane >> 5;
  int l2   = lane & 31;
  int h    = l2 >> 3;       // head for this lane's dims (both OUTD)
  int beg = offs[wid], end = offs[wid+1];
  float adh = ald[(size_t)wid*4 + h];

  float acc[VEC];
  #pragma unroll
  for (int k=0;k<VEC;k++) acc[k] = 0.f;
  float den = 0.f;

  int last = end - 1;
  for (int j = beg + half; j < end; j += 8){
    int j1 = j+2, j2 = j+4, j3 = j+6;
    bool p1 = j1 < end, p2 = j2 < end, p3 = j3 < end;
    int s0 = csr[j];
    int s1 = csr[p1 ? j1 : last];
    int s2 = csr[p2 ? j2 : last];
    int s3 = csr[p3 ? j3 : last];
    float v0[VEC], v1[VEC], v2[VEC], v3[VEC];
    if constexpr (VEC == 4){
      ld4(hW, (size_t)s0*32 + l2, v0);
      ld4(hW, (size_t)s1*32 + l2, v1);
      ld4(hW, (size_t)s2*32 + l2, v2);
      ld4(hW, (size_t)s3*32 + l2, v3);
    } else {
      ld2v(hW, (size_t)s0*32 + l2, v0);
      ld2v(hW, (size_t)s1*32 + l2, v1);
      ld2v(hW, (size_t)s2*32 + l2, v2);
      ld2v(hW, (size_t)s3*32 + l2, v3);
    }
    float e0 = als[(size_t)s0*4 + h] + adh;
    float e1 = als[(size_t)s1*4 + h] + adh;
    float e2 = als[(size_t)s2*4 + h] + adh;
    float e3 = als[(size_t)s3*4 + h] + adh;
    e0 = (e0>0.f)? e0 : 0.2f*e0;
    e1 = (e1>0.f)? e1 : 0.2f*e1;
    e2 = (e2>0.f)? e2 : 0.2f*e2;
    e3 = (e3>0.f)? e3 : 0.2f*e3;
    float ex0 = __expf(e0);
    float ex1 = p1 ? __expf(e1) : 0.f;
    float ex2 = p2 ? __expf(e2) : 0.f;
    float ex3 = p3 ? __expf(e3) : 0.f;
    den += (ex0 + ex1) + (ex2 + ex3);
    #pragma unroll
    for (int k=0;k<VEC;k++){
      acc[k] = fmaf(ex0, v0[k], acc[k]);
      acc[k] = fmaf(ex1, v1[k], acc[k]);
      acc[k] = fmaf(ex2, v2[k], acc[k]);
      acc[k] = fmaf(ex3, v3[k], acc[k]);
    }
  }

  // combine the two halves
  den += __shfl_xor(den, 32);
  #pragma unroll
  for (int k=0;k<VEC;k++) acc[k] += __shfl_xor(acc[k], 32);

  if (half == 0){
    float inv = 1.f / (den + 1e-16f);
    float o[VEC];
    if constexpr (VEC == 4){
      const float4 bv = ((const float4*)bias)[l2];
      o[0] = fmaf(acc[0], inv, bv.x);
      o[1] = fmaf(acc[1], inv, bv.y);
      o[2] = fmaf(acc[2], inv, bv.z);
      o[3] = fmaf(acc[3], inv, bv.w);
      #pragma unroll
      for (int k=0;k<4;k++) o[k] = (o[k]>0.f)? o[k] : 0.f;
      st4(hout, (size_t)wid*32 + l2, o);
    } else {
      const float2 bv = ((const float2*)bias)[l2];
      o[0] = fmaf(acc[0], inv, bv.x);
      o[1] = fmaf(acc[1], inv, bv.y);
      o[0] = (o[0]>0.f)? o[0] : 0.f;
      o[1] = (o[1]>0.f)? o[1] : 0.f;
      sth2(hout, (size_t)wid*32 + l2, make_float2(o[0], o[1]));
    }
  }
}

// ---------- classifier v3: out[n,40] = h[n,64] @ Wc + bc (fp32 output) -------
template<typename T>
__global__ __launch_bounds__(256) void classifier_kernel(const T* __restrict__ h,
      const float* __restrict__ Wc, const float* __restrict__ bc,
      float* __restrict__ out, int n){
  __shared__ float As[128*65];    // 33.3 KB
  __shared__ float Ws[64*40];     // 10.24 KB
  __shared__ float bs[40];
  int t = threadIdx.x;
  int r0b = blockIdx.x * 128;

  for (int i=t; i<2560; i+=256) Ws[i] = Wc[i];
  if (t < 40) bs[t] = bc[t];

  for (int i=t; i < 128*64; i += 256){
    int r = i >> 6, k = i & 63;
    int gr = r0b + r;
    float a = 0.f;
    if (gr < n) a = ldh(h, (size_t)gr*64 + k);
    As[r*65 + k] = a;
  }
  __syncthreads();

  int tx = t & 7;        // cols tx*5 .. tx*5+4
  int ty = t >> 3;       // rows ty*4 .. ty*4+3
  float acc[4][5];
  #pragma unroll
  for (int r=0;r<4;r++)
    #pragma unroll
    for (int c=0;c<5;c++) acc[r][c] = 0.f;

  #pragma unroll 8
  for (int k=0; k<64; k++){
    float a0 = As[(ty*4+0)*65 + k];
    float a1 = As[(ty*4+1)*65 + k];
    float a2 = As[(ty*4+2)*65 + k];
    float a3 = As[(ty*4+3)*65 + k];
    float w[5];
    #pragma unroll
    for (int c=0;c<5;c++) w[c] = Ws[k*40 + tx*5 + c];
    #pragma unroll
    for (int c=0;c<5;c++){
      acc[0][c] = fmaf(a0, w[c], acc[0][c]);
      acc[1][c] = fmaf(a1, w[c], acc[1][c]);
      acc[2][c] = fmaf(a2, w[c], acc[2][c]);
      acc[3][c] = fmaf(a3, w[c], acc[3][c]);
    }
  }

  #pragma unroll
  for (int r=0;r<4;r++){
    int gr = r0b + ty*4 + r;
    if (gr < n){
      #pragma unroll
      for (int c=0;c<5;c++)
        out[(size_t)gr*40 + tx*5 + c] = acc[r][c] + bs[tx*5 + c];
    }
  }
}

// ---------------- pipeline ----------------
template<typename TM, typename TO>
static void run_pipeline(void* const* d_in, int ei_idx, int pbase, int n, int E,
                         void* d_out, int out_size, void* d_ws, size_t ws_size,
                         hipStream_t stream){
  const void* x = d_in[0];
  const int* ei = (const int*)d_in[ei_idx];
  float* out = (float*)d_out;           // fp32 output
  int Etot = E + n;

  char* p = (char*)d_ws;
  auto alloc = [&](size_t bytes)->char* {
    char* r = p; p += (bytes + 255) & ~(size_t)255; return r;
  };
  int*   flag   = (int*)  alloc(256);
  int*   eflag  = (int*)  alloc(256);
  int*   counts = (int*)  alloc((size_t)n * 4);
  float* als    = (float*)alloc((size_t)n * 16);
  float* ald    = (float*)alloc((size_t)n * 16);
  float* prm    = (float*)alloc(48000 * 4);
  // split-fp16 fragment-major W copies (wfrag_kernel output)
  uint16_t* wh0 = (uint16_t*)alloc(16384 * 2);
  uint16_t* wl0 = (uint16_t*)alloc(16384 * 2);
  uint16_t* wh1 = (uint16_t*)alloc(16384 * 2);
  uint16_t* wl1 = (uint16_t*)alloc(16384 * 2);
  uint16_t* wh2 = (uint16_t*)alloc(8192 * 2);
  uint16_t* wl2 = (uint16_t*)alloc(8192 * 2);

  // csr/offs/rank/bsums in d_out (fp32 out: 16 MB; dead until classifier)
  size_t csr_b  = ((size_t)Etot * 4 + 255) & ~(size_t)255;
  size_t offs_b = ((size_t)(n + 1) * 4 + 255) & ~(size_t)255;
  size_t rank_b = ((size_t)Etot * 4 + 255) & ~(size_t)255;
  size_t out_bytes = (size_t)out_size * 4;
  int *csr, *offs, *rank, *bsums;
  if (csr_b + offs_b + rank_b + 4096 <= out_bytes){
    char* q = (char*)d_out;
    csr   = (int*)q;
    offs  = (int*)(q + csr_b);
    rank  = (int*)(q + csr_b + offs_b);
    bsums = (int*)(q + csr_b + offs_b + rank_b);
  } else {
    csr   = (int*)alloc((size_t)Etot * 4);
    offs  = (int*)alloc((size_t)(n + 1) * 4);
    rank  = (int*)alloc((size_t)Etot * 4);
    bsums = (int*)alloc(4096);
  }
  TM* bufMid = (TM*)alloc((size_t)n * 128 * sizeof(TM));
  TO* bufOut = (TO*)alloc((size_t)n * 128 * sizeof(TO));

  PP pp;
  static const int cnts[14] = {16384,128,128,128, 16384,128,128,128, 8192,64,64,64, 2560,40};
  int off = 0;
  for (int i = 0; i < 14; i++){
    pp.src[i] = d_in[pbase + i];
    pp.cnt[i] = cnts[i];
    pp.off[i] = off;
    off += cnts[i];
  }
  const float* W0  = prm + pp.off[0];
  const float* as0 = prm + pp.off[1];
  const float* ad0 = prm + pp.off[2];
  const float* b0  = prm + pp.off[3];
  const float* W1  = prm + pp.off[4];
  const float* as1 = prm + pp.off[5];
  const float* ad1 = prm + pp.off[6];
  const float* b1  = prm + pp.off[7];
  const float* W2  = prm + pp.off[8];
  const float* as2 = prm + pp.off[9];
  const float* ad2 = prm + pp.off[10];
  const float* b2  = prm + pp.off[11];
  const float* Wc  = prm + pp.off[12];
  const float* bc  = prm + pp.off[13];

  hipMemsetAsync(counts, 0, (size_t)n * 4, stream);

  detect_kernel<<<1, 64, 0, stream>>>((const uint32_t*)x, flag);
  edetect_kernel<<<1, 64, 0, stream>>>((const uint32_t*)ei, eflag);
  cvt_params_kernel<<<14, 256, 0, stream>>>(pp, prm, flag);
  // W -> fragment-major split-fp16 (2048/2048/1024 entries)
  wfrag_kernel<<<8, 256, 0, stream>>>(W0, wh0, wl0, 128, 128);
  wfrag_kernel<<<8, 256, 0, stream>>>(W1, wh1, wl1, 128, 128);
  wfrag_kernel<<<4, 256, 0, stream>>>(W2, wh2, wl2, 128, 64);

  count_kernel<<<(Etot + 255)/256, 256, 0, stream>>>(ei, eflag, counts, rank, E, n);
  int nb = (n + SCAN_CHUNK - 1) / SCAN_CHUNK;
  scan1_kernel<<<nb, SCAN_BS, 0, stream>>>(counts, offs, bsums, n);
  scan2_kernel<<<1, 1024, 0, stream>>>(bsums, nb);
  scan3_kernel<<<(n + 1 + 255)/256, 256, 0, stream>>>(offs, bsums, n, Etot);
  fill_kernel<<<(Etot + 255)/256, 256, 0, stream>>>(ei, eflag, offs, rank, csr, E, n);

  int gg   = (n + 127) / 128;    // gemm_mfma: 128 rows/block
  int log_grid = (n*4 + 255) / 256;
  int agg_grid = (n + 3) / 4;
  int cls_grid = (n + 127) / 128;

  // layer 0: x -> bufMid -> bufOut   (x dtype runtime-detected; expect fp32)
  gemm_mfma<128,128,true,TO,TM><<<gg, 256, 0, stream>>>(x, wh0, wl0, bufMid, n, flag);
  logits_kernel<128,32,TM><<<log_grid, 256, 0, stream>>>(bufMid, as0, ad0, als, ald, n);
  aggregate_kernel<128,TM,TO><<<agg_grid, 256, 0, stream>>>(bufMid, als, ald, offs, csr, b0, bufOut, n);

  // layer 1
  gemm_mfma<128,128,false,TO,TM><<<gg, 256, 0, stream>>>(bufOut, wh1, wl1, bufMid, n, flag);
  logits_kernel<128,32,TM><<<log_grid, 256, 0, stream>>>(bufMid, as1, ad1, als, ald, n);
  aggregate_kernel<128,TM,TO><<<agg_grid, 256, 0, stream>>>(bufMid, als, ald, offs, csr, b1, bufOut, n);

  // layer 2 (outd=64)
  gemm_mfma<128,64,false,TO,TM><<<gg, 256, 0, stream>>>(bufOut, wh2, wl2, bufMid, n, flag);
  logits_kernel<64,16,TM><<<log_grid, 256, 0, stream>>>(bufMid, as2, ad2, als, ald, n);
  aggregate_kernel<64,TM,TO><<<agg_grid, 256, 0, stream>>>(bufMid, als, ald, offs, csr, b2, bufOut, n);

  // classifier: fp32 writes, fully overwrites d_out
  classifier_kernel<TO><<<cls_grid, 256, 0, stream>>>(bufOut, Wc, bc, out, n);
}

// ---------------- launcher ----------------
extern "C" void kernel_launch(void* const* d_in, const int* in_sizes, int n_in,
                              void* d_out, int out_size, void* d_ws, size_t ws_size,
                              hipStream_t stream) {
  int n = in_sizes[0] / 128;

  int ei_idx, pbase;
  if (n_in >= 2 && in_sizes[1] > 1000000) { ei_idx = 1;        pbase = 2; }   // dict order
  else                                    { ei_idx = n_in - 1; pbase = 1; }   // signature order
  int E = in_sizes[ei_idx] / 2;

  size_t base = 512
              + (((size_t)n*4  + 255) & ~(size_t)255)
              + 2*(((size_t)n*16 + 255) & ~(size_t)255)
              + ((48000*4 + 255) & ~(size_t)255)
              + 4*((16384*2 + 255) & ~(size_t)255)     // wh0/wl0/wh1/wl1
              + 2*((8192*2 + 255) & ~(size_t)255)      // wh2/wl2
              + 65536
              + 3*(((size_t)(E + n)*4 + 255) & ~(size_t)255);  // csr/offs/rank fallback
  size_t f32buf  = ((size_t)n*128*4 + 255) & ~(size_t)255;
  size_t h16buf  = ((size_t)n*128*2 + 255) & ~(size_t)255;

  if (ws_size >= base + f32buf + h16buf)       // tier 1: fp16 gather buf, fp32 h
    run_pipeline<h16, float>(d_in, ei_idx, pbase, n, E, d_out, out_size, d_ws, ws_size, stream);
  else                                         // tier 2: all 16-bit
    run_pipeline<h16, uint16_t>(d_in, ei_idx, pbase, n, E, d_out, out_size, d_ws, ws_size, stream);
}

// Round 11
// 555.860 us; speedup vs baseline: 1.2213x; 1.0543x over previous
//
#include <hip/hip_runtime.h>
#include <hip/hip_bf16.h>
#include <hip/hip_fp16.h>
#include <stdint.h>

typedef __hip_bfloat16 bf16;
typedef _Float16 f16;
typedef __attribute__((ext_vector_type(8))) _Float16 f16x8;
typedef __attribute__((ext_vector_type(4))) _Float16 f16x4;
typedef __attribute__((ext_vector_type(2))) _Float16 f16x2;
typedef __attribute__((ext_vector_type(4))) float    f32x4;

__device__ __forceinline__ float us2f(uint16_t u){
  union { uint32_t i; float f; } v; v.i = ((uint32_t)u) << 16; return v.f;
}
__device__ __forceinline__ float bflo(uint32_t u){
  union { uint32_t i; float f; } v; v.i = u << 16; return v.f;
}
__device__ __forceinline__ float bfhi(uint32_t u){
  union { uint32_t i; float f; } v; v.i = u & 0xffff0000u; return v.f;
}
__device__ __forceinline__ uint16_t f2u16(float f){
  union { bf16 b; uint16_t u; } v; v.b = __float2bfloat16(f); return v.u;
}
// fp16 storage type (distinct from uint16_t=bf16 for overload resolution)
struct h16 { uint16_t v; };

// storage helpers: h buffers are float, bf16(uint16_t), or fp16(h16)
__device__ __forceinline__ float  ldh (const float* p, size_t i){ return p[i]; }
__device__ __forceinline__ float  ldh (const uint16_t* p, size_t i){ return us2f(p[i]); }
__device__ __forceinline__ float  ldh (const h16* p, size_t i){ return __half2float(((const __half*)p)[i]); }
__device__ __forceinline__ float2 ldh2(const float* p, size_t i){ return ((const float2*)p)[i]; }
__device__ __forceinline__ float2 ldh2(const uint16_t* p, size_t i){
  uint32_t u = ((const uint32_t*)p)[i]; return make_float2(bflo(u), bfhi(u));
}
__device__ __forceinline__ float2 ldh2(const h16* p, size_t i){
  __half2 u = ((const __half2*)p)[i];
  return make_float2(__low2float(u), __high2float(u));
}
__device__ __forceinline__ void sth (float* p, size_t i, float v){ p[i] = v; }
__device__ __forceinline__ void sth (uint16_t* p, size_t i, float v){ p[i] = f2u16(v); }
__device__ __forceinline__ void sth (h16* p, size_t i, float v){ ((__half*)p)[i] = __float2half(v); }
__device__ __forceinline__ void sth2(float* p, size_t i, float2 v){ ((float2*)p)[i] = v; }
__device__ __forceinline__ void sth2(uint16_t* p, size_t i, float2 v){
  ((uint32_t*)p)[i] = (uint32_t)f2u16(v.x) | ((uint32_t)f2u16(v.y) << 16);
}
__device__ __forceinline__ void sth2(h16* p, size_t i, float2 v){
  ((__half2*)p)[i] = __float22half2_rn(v);
}
// gather loaders for the aggregate: fp16 buffers return _Float16 (cvt fuses
// into v_fma_mix at the consuming fma); fp32/bf16 return float.
template<typename T> struct vtt { using t = float; };
template<> struct vtt<h16> { using t = f16; };

__device__ __forceinline__ void ld4(const float* p, size_t i4, float* o){
  float4 v = ((const float4*)p)[i4]; o[0]=v.x; o[1]=v.y; o[2]=v.z; o[3]=v.w;
}
__device__ __forceinline__ void ld4(const uint16_t* p, size_t i4, float* o){
  uint2 u = ((const uint2*)p)[i4];
  o[0]=bflo(u.x); o[1]=bfhi(u.x); o[2]=bflo(u.y); o[3]=bfhi(u.y);
}
__device__ __forceinline__ void ld4(const h16* p, size_t i4, f16* o){
  f16x4 v = ((const f16x4*)p)[i4];
  o[0]=v[0]; o[1]=v[1]; o[2]=v[2]; o[3]=v[3];
}
__device__ __forceinline__ void ld2v(const float* p, size_t i2, float* o){
  float2 v = ((const float2*)p)[i2]; o[0]=v.x; o[1]=v.y;
}
__device__ __forceinline__ void ld2v(const uint16_t* p, size_t i2, float* o){
  uint32_t u = ((const uint32_t*)p)[i2]; o[0]=bflo(u); o[1]=bfhi(u);
}
__device__ __forceinline__ void ld2v(const h16* p, size_t i2, f16* o){
  f16x2 v = ((const f16x2*)p)[i2]; o[0]=v[0]; o[1]=v[1];
}
__device__ __forceinline__ void st4(float* p, size_t i4, const float* o){
  ((float4*)p)[i4] = make_float4(o[0],o[1],o[2],o[3]);
}
__device__ __forceinline__ void st4(uint16_t* p, size_t i4, const float* o){
  uint2 u;
  u.x = (uint32_t)f2u16(o[0]) | ((uint32_t)f2u16(o[1]) << 16);
  u.y = (uint32_t)f2u16(o[2]) | ((uint32_t)f2u16(o[3]) << 16);
  ((uint2*)p)[i4] = u;
}
__device__ __forceinline__ void st4(h16* p, size_t i4, const float* o){
  ((__half2*)p)[i4*2]   = __float22half2_rn(make_float2(o[0],o[1]));
  ((__half2*)p)[i4*2+1] = __float22half2_rn(make_float2(o[2],o[3]));
}
// 8-wide consecutive loaders (32B-aligned base), for MFMA A-frags
__device__ __forceinline__ void ld8(const float* p, size_t i, float* o){
  float4 a = ((const float4*)(p+i))[0];
  float4 b = ((const float4*)(p+i))[1];
  o[0]=a.x; o[1]=a.y; o[2]=a.z; o[3]=a.w; o[4]=b.x; o[5]=b.y; o[6]=b.z; o[7]=b.w;
}
__device__ __forceinline__ void ld8(const uint16_t* p, size_t i, float* o){
  uint4 u = *(const uint4*)(p+i);
  o[0]=bflo(u.x); o[1]=bfhi(u.x); o[2]=bflo(u.y); o[3]=bfhi(u.y);
  o[4]=bflo(u.z); o[5]=bfhi(u.z); o[6]=bflo(u.w); o[7]=bfhi(u.w);
}
__device__ __forceinline__ void ld8(const h16* p, size_t i, float* o){
  const __half2* q = (const __half2*)(p+i);
  #pragma unroll
  for (int j=0;j<4;j++){ __half2 u=q[j]; o[2*j]=__low2float(u); o[2*j+1]=__high2float(u); }
}

// ---------------- dtype detections (merged) ----------------
__global__ void detect2_kernel(const uint32_t* __restrict__ x, const uint32_t* __restrict__ ei,
                               int* __restrict__ flag, int* __restrict__ eflag){
  int t = threadIdx.x;
  if (t < 64){
    uint32_t w = x[t];
    uint32_t e = (w >> 7) & 0xffu;
    bool looks_bf16 = (e >= 118 && e <= 134);
    unsigned long long m = __ballot(looks_bf16);
    if (t == 0) flag[0] = (__popcll(m) >= 32) ? 0 : 1;   // 1 = fp32 inputs
  } else {
    int lane = t - 64;
    uint32_t w = ei[lane];
    bool ok = (lane & 1) ? (w == 0u) : true;
    unsigned long long m = __ballot(ok);
    if (lane == 0) eflag[0] = (__popcll(m) == 64) ? 1 : 0;  // 1 = int64 edges
  }
}

// ---------------- params -> canonical fp32 copies ----------------
struct PP {
  const void* src[14];
  int off[14];
  int cnt[14];
};

__global__ void cvt_params_kernel(PP pp, float* __restrict__ dst, const int* __restrict__ flag){
  int b = blockIdx.x;
  int cnt = pp.cnt[b];
  float* d = dst + pp.off[b];
  if (flag[0] != 0){
    const float* s = (const float*)pp.src[b];
    for (int i = threadIdx.x; i < cnt; i += 256) d[i] = s[i];
  } else {
    const uint16_t* s = (const uint16_t*)pp.src[b];
    for (int i = threadIdx.x; i < cnt; i += 256) d[i] = us2f(s[i]);
  }
}

// ---- all W matrices -> fragment-major split-fp16 in ONE kernel ----
// Entry e = (c*CT + ct)*64 + lane; elem i: k = 32c + 8*(lane>>4) + i,
// m = 16ct + (lane&15); cols >= Ms zero-padded (classifier Wc 40->48).
struct WF {
  int src[4];   // float offset into prm
  int dst[4];   // half offset into whl (wh; wl = wh + cnt)
  int cnt[4];   // elems per split half
  int K[4], Ms[4], Mp[4];
  int blk0[5];
};

__global__ void wfrag4_kernel(const float* __restrict__ prm, uint16_t* __restrict__ whl, WF wf){
  int b = blockIdx.x;
  int w = 3;
  if (b < wf.blk0[1]) w = 0; else if (b < wf.blk0[2]) w = 1; else if (b < wf.blk0[3]) w = 2;
  int e = (b - wf.blk0[w])*256 + threadIdx.x;
  int CT = wf.Mp[w] >> 4, KC = wf.K[w] >> 5;
  if (e >= KC*CT*64) return;
  const float* W = prm + wf.src[w];
  uint16_t* wh = whl + wf.dst[w];
  uint16_t* wl = wh + wf.cnt[w];
  int Ms = wf.Ms[w];
  int l = e & 63, t = e >> 6;
  int ct = t % CT, c = t / CT;
  int kbase = c*32 + (l>>4)*8;
  int m = ct*16 + (l&15);
  #pragma unroll
  for (int i=0;i<8;i++){
    float v = (m < Ms) ? W[(size_t)(kbase+i)*Ms + m] : 0.f;
    f16 h = (f16)v;
    f16 r = (f16)(v - (float)h);
    union { f16 f; uint16_t u; } ch, cr; ch.f = h; cr.f = r;
    wh[(size_t)e*8 + i] = ch.u;
    wl[(size_t)e*8 + i] = cr.u;
  }
}

// ---------------- CSR build ----------------
// rank trick: the ONLY atomic pass. rank[i] = old count (coalesced write);
// fill then needs no atomic at all.
__global__ void count_kernel(const int* __restrict__ ei, const int* __restrict__ eflag,
                             int* __restrict__ counts, int* __restrict__ rank,
                             int E, int n){
  int i = blockIdx.x * 256 + threadIdx.x;
  if (i >= E + n) return;
  int d;
  if (i < E) d = eflag[0] ? ei[2*(size_t)E + 2*(size_t)i] : ei[(size_t)E + i];
  else       d = i - E;
  rank[i] = atomicAdd(&counts[d], 1);
}

#define SCAN_BS 256
#define SCAN_CHUNK 1024

__global__ void scan1_kernel(const int* __restrict__ counts, int* __restrict__ offs,
                             int* __restrict__ bsums, int n){
  __shared__ int sdata[SCAN_BS];
  int b = blockIdx.x, t = threadIdx.x;
  int base = b * SCAN_CHUNK + t * 4;
  int v[4]; int s = 0;
  #pragma unroll
  for (int j=0;j<4;j++){ int idx = base+j; v[j] = (idx<n)? counts[idx] : 0; s += v[j]; }
  sdata[t] = s;
  __syncthreads();
  for (int off=1; off<SCAN_BS; off<<=1){
    int x = (t>=off)? sdata[t-off] : 0;
    __syncthreads();
    sdata[t] += x;
    __syncthreads();
  }
  int run = sdata[t] - s;
  #pragma unroll
  for (int j=0;j<4;j++){ int idx = base+j; if (idx<n) offs[idx] = run; run += v[j]; }
  if (t == SCAN_BS-1) bsums[b] = sdata[t];
}

__global__ void scan2_kernel(int* __restrict__ bsums, int nb){
  __shared__ int sdata[1024];
  int t = threadIdx.x;
  int v = (t<nb)? bsums[t] : 0;
  sdata[t] = v;
  __syncthreads();
  for (int off=1; off<1024; off<<=1){
    int x = (t>=off)? sdata[t-off] : 0;
    __syncthreads();
    sdata[t] += x;
    __syncthreads();
  }
  if (t<nb) bsums[t] = sdata[t] - v;
}

__global__ void scan3_kernel(int* __restrict__ offs, const int* __restrict__ bsums,
                             int n, int total){
  int i = blockIdx.x * 256 + threadIdx.x;
  if (i < n) offs[i] += bsums[i / SCAN_CHUNK];
  if (i == n) offs[n] = total;
}

// atomic-free fill: coalesced ei+rank reads, L2-resident offs gather, scatter store
__global__ void fill_kernel(const int* __restrict__ ei, const int* __restrict__ eflag,
                            const int* __restrict__ offs, const int* __restrict__ rank,
                            int* __restrict__ csr, int E, int n){
  int i = blockIdx.x * 256 + threadIdx.x;
  if (i >= E + n) return;
  int s, d;
  if (i < E){
    if (eflag[0]){ s = ei[2*(size_t)i]; d = ei[2*(size_t)E + 2*(size_t)i]; }
    else         { s = ei[i];           d = ei[(size_t)E + i]; }
  } else { s = i - E; d = i - E; }
  csr[offs[d] + rank[i]] = s;
}

// ---- GEMM: split-fp16 MFMA, barrier-free, LDS-free ----
// acc += Ah*Wh + Al*Wh + Ah*Wl (3 MFMA, fp32 accumulate), residual ~eps^2.
// C/D layout per m89: col=lane&15, row=(lane>>4)*4+reg.
template<int K, int M, bool DET, typename TA, typename TC>
__global__ __launch_bounds__(256) void gemm_mfma(const void* __restrict__ Ap,
    const uint16_t* __restrict__ whb, const uint16_t* __restrict__ wlb,
    TC* __restrict__ C, int n, const int* __restrict__ flag){
  constexpr int CT = M/16;     // col tiles
  constexpr int KC = K/32;     // k chunks
  constexpr int RT = 2;        // row tiles per wave (32 rows)
  int tid = threadIdx.x;
  int wv  = tid >> 6, l = tid & 63;
  int lr  = l & 15, kg = l >> 4;
  int r0  = blockIdx.x*(64*RT) + wv*(16*RT);

  bool f32 = DET ? (flag[0] != 0) : false;
  const uint16_t* Au = (const uint16_t*)Ap;
  const float*    Af = (const float*)Ap;
  const TA*       At = (const TA*)Ap;
  const f16x8* Wh = (const f16x8*)whb;
  const f16x8* Wl = (const f16x8*)wlb;

  f32x4 acc[RT][CT];
  #pragma unroll
  for (int rt=0;rt<RT;rt++)
    #pragma unroll
    for (int ct=0;ct<CT;ct++) acc[rt][ct] = (f32x4){0.f,0.f,0.f,0.f};

  for (int c=0; c<KC; c++){
    f16x8 ah[RT], al[RT];
    #pragma unroll
    for (int rt=0;rt<RT;rt++){
      int arow = r0 + rt*16 + lr;
      if (arow > n-1) arow = n-1;
      size_t idx = (size_t)arow*K + c*32 + kg*8;
      float av[8];
      if (DET){
        if (f32) ld8(Af, idx, av);
        else     ld8(Au, idx, av);
      } else {
        ld8(At, idx, av);
      }
      #pragma unroll
      for (int i=0;i<8;i++){
        f16 h = (f16)av[i];
        ah[rt][i] = h;
        al[rt][i] = (f16)(av[i] - (float)h);
      }
    }
    #pragma unroll
    for (int ct=0;ct<CT;ct++){
      f16x8 bh = Wh[(size_t)(c*CT + ct)*64 + l];
      f16x8 bl = Wl[(size_t)(c*CT + ct)*64 + l];
      #pragma unroll
      for (int rt=0;rt<RT;rt++){
        acc[rt][ct] = __builtin_amdgcn_mfma_f32_16x16x32_f16(ah[rt], bh, acc[rt][ct], 0, 0, 0);
        acc[rt][ct] = __builtin_amdgcn_mfma_f32_16x16x32_f16(al[rt], bh, acc[rt][ct], 0, 0, 0);
        acc[rt][ct] = __builtin_amdgcn_mfma_f32_16x16x32_f16(ah[rt], bl, acc[rt][ct], 0, 0, 0);
      }
    }
  }

  #pragma unroll
  for (int rt=0;rt<RT;rt++){
    #pragma unroll
    for (int r=0;r<4;r++){
      int orow = r0 + rt*16 + kg*4 + r;
      if (orow < n){
        #pragma unroll
        for (int ct=0;ct<CT;ct++)
          sth(C, (size_t)orow*M + ct*16 + lr, acc[rt][ct][r]);
      }
    }
  }
}

// ---- classifier as split-fp16 MFMA: out[n,40] = h[n,64] @ Wc + bc ----
// Wc padded to 64x48 fragment-major (wfrag4 w=3). K=64 -> KC=2, CT=3.
// fp32 bias epilogue, cols >= 40 masked. No relu.
template<typename TA>
__global__ __launch_bounds__(256) void gemm_cls(const TA* __restrict__ A,
    const uint16_t* __restrict__ whb, const uint16_t* __restrict__ wlb,
    const float* __restrict__ bc, float* __restrict__ out, int n){
  constexpr int CT = 3, KC = 2, RT = 2;
  int tid = threadIdx.x;
  int wv  = tid >> 6, l = tid & 63;
  int lr  = l & 15, kg = l >> 4;
  int r0  = blockIdx.x*128 + wv*32;
  const f16x8* Wh = (const f16x8*)whb;
  const f16x8* Wl = (const f16x8*)wlb;

  f32x4 acc[RT][CT];
  #pragma unroll
  for (int rt=0;rt<RT;rt++)
    #pragma unroll
    for (int ct=0;ct<CT;ct++) acc[rt][ct] = (f32x4){0.f,0.f,0.f,0.f};

  for (int c=0; c<KC; c++){
    f16x8 ah[RT], al[RT];
    #pragma unroll
    for (int rt=0;rt<RT;rt++){
      int arow = r0 + rt*16 + lr;
      if (arow > n-1) arow = n-1;
      size_t idx = (size_t)arow*64 + c*32 + kg*8;
      float av[8];
      ld8(A, idx, av);
      #pragma unroll
      for (int i=0;i<8;i++){
        f16 h = (f16)av[i];
        ah[rt][i] = h;
        al[rt][i] = (f16)(av[i] - (float)h);
      }
    }
    #pragma unroll
    for (int ct=0;ct<CT;ct++){
      f16x8 bh = Wh[(size_t)(c*CT + ct)*64 + l];
      f16x8 bl = Wl[(size_t)(c*CT + ct)*64 + l];
      #pragma unroll
      for (int rt=0;rt<RT;rt++){
        acc[rt][ct] = __builtin_amdgcn_mfma_f32_16x16x32_f16(ah[rt], bh, acc[rt][ct], 0, 0, 0);
        acc[rt][ct] = __builtin_amdgcn_mfma_f32_16x16x32_f16(al[rt], bh, acc[rt][ct], 0, 0, 0);
        acc[rt][ct] = __builtin_amdgcn_mfma_f32_16x16x32_f16(ah[rt], bl, acc[rt][ct], 0, 0, 0);
      }
    }
  }

  #pragma unroll
  for (int rt=0;rt<RT;rt++){
    #pragma unroll
    for (int r=0;r<4;r++){
      int orow = r0 + rt*16 + kg*4 + r;
      if (orow < n){
        #pragma unroll
        for (int ct=0;ct<CT;ct++){
          int col = ct*16 + lr;
          if (col < 40)
            out[(size_t)orow*40 + col] = acc[rt][ct][r] + bc[col];
        }
      }
    }
  }
}

// ---------------- per-node attention logits ----------------
template<int OUTD, int HD, typename T>
__global__ void logits_kernel(const T* __restrict__ hW, const float* __restrict__ a_src,
                              const float* __restrict__ a_dst, float* __restrict__ als,
                              float* __restrict__ ald, int n){
  int i = blockIdx.x * 256 + threadIdx.x;   // i = node*4 + h
  if (i >= n*4) return;
  int node = i >> 2, h = i & 3;
  const T* hp = hW + (size_t)node*OUTD + h*HD;
  float ss = 0.f, sd = 0.f;
  #pragma unroll
  for (int d2=0; d2<HD/2; d2++){
    float2 v = ldh2(hp, d2);
    int b = h*HD + 2*d2;
    ss += v.x*a_src[b] + v.y*a_src[b+1];
    sd += v.x*a_dst[b] + v.y*a_dst[b+1];
  }
  als[i] = ss; ald[i] = sd;
}

// ---------------- aggregation: one wave per destination node ----------------
// SINGLE PASS (no segment-max; |e| << 88 so exp is safe). Fully predicated:
// 4 row-gathers per half-wave every iteration, OOB slots clamp with ex=0.
// v6: fp16 gathers stay _Float16 until the fma -> v_fma_mix_f32 (cvt fused).
template<int OUTD, typename TIN, typename TOUT>
__global__ __launch_bounds__(256) void aggregate_kernel(const TIN* __restrict__ hW,
            const float* __restrict__ als, const float* __restrict__ ald,
            const int* __restrict__ offs, const int* __restrict__ csr,
            const float* __restrict__ bias, TOUT* __restrict__ hout, int n){
  constexpr int VEC = OUTD / 32;          // 4 (OUTD=128) or 2 (OUTD=64)
  using VT = typename vtt<TIN>::t;
  int wid = (blockIdx.x * 256 + threadIdx.x) >> 6;   // node
  if (wid >= n) return;
  int lane = threadIdx.x & 63;
  int half = lane >> 5;
  int l2   = lane & 31;
  int h    = l2 >> 3;       // head for this lane's dims (both OUTD)
  int beg = offs[wid], end = offs[wid+1];
  float adh = ald[(size_t)wid*4 + h];

  float acc[VEC];
  #pragma unroll
  for (int k=0;k<VEC;k++) acc[k] = 0.f;
  float den = 0.f;

  int last = end - 1;
  for (int j = beg + half; j < end; j += 8){
    int j1 = j+2, j2 = j+4, j3 = j+6;
    bool p1 = j1 < end, p2 = j2 < end, p3 = j3 < end;
    int s0 = csr[j];
    int s1 = csr[p1 ? j1 : last];
    int s2 = csr[p2 ? j2 : last];
    int s3 = csr[p3 ? j3 : last];
    VT v0[VEC], v1[VEC], v2[VEC], v3[VEC];
    if constexpr (VEC == 4){
      ld4(hW, (size_t)s0*32 + l2, v0);
      ld4(hW, (size_t)s1*32 + l2, v1);
      ld4(hW, (size_t)s2*32 + l2, v2);
      ld4(hW, (size_t)s3*32 + l2, v3);
    } else {
      ld2v(hW, (size_t)s0*32 + l2, v0);
      ld2v(hW, (size_t)s1*32 + l2, v1);
      ld2v(hW, (size_t)s2*32 + l2, v2);
      ld2v(hW, (size_t)s3*32 + l2, v3);
    }
    float e0 = als[(size_t)s0*4 + h] + adh;
    float e1 = als[(size_t)s1*4 + h] + adh;
    float e2 = als[(size_t)s2*4 + h] + adh;
    float e3 = als[(size_t)s3*4 + h] + adh;
    e0 = (e0>0.f)? e0 : 0.2f*e0;
    e1 = (e1>0.f)? e1 : 0.2f*e1;
    e2 = (e2>0.f)? e2 : 0.2f*e2;
    e3 = (e3>0.f)? e3 : 0.2f*e3;
    float ex0 = __expf(e0);
    float ex1 = p1 ? __expf(e1) : 0.f;
    float ex2 = p2 ? __expf(e2) : 0.f;
    float ex3 = p3 ? __expf(e3) : 0.f;
    den += (ex0 + ex1) + (ex2 + ex3);
    #pragma unroll
    for (int k=0;k<VEC;k++){
      acc[k] = fmaf(ex0, (float)v0[k], acc[k]);
      acc[k] = fmaf(ex1, (float)v1[k], acc[k]);
      acc[k] = fmaf(ex2, (float)v2[k], acc[k]);
      acc[k] = fmaf(ex3, (float)v3[k], acc[k]);
    }
  }

  // combine the two halves
  den += __shfl_xor(den, 32);
  #pragma unroll
  for (int k=0;k<VEC;k++) acc[k] += __shfl_xor(acc[k], 32);

  if (half == 0){
    float inv = 1.f / (den + 1e-16f);
    float o[VEC];
    if constexpr (VEC == 4){
      const float4 bv = ((const float4*)bias)[l2];
      o[0] = fmaf(acc[0], inv, bv.x);
      o[1] = fmaf(acc[1], inv, bv.y);
      o[2] = fmaf(acc[2], inv, bv.z);
      o[3] = fmaf(acc[3], inv, bv.w);
      #pragma unroll
      for (int k=0;k<4;k++) o[k] = (o[k]>0.f)? o[k] : 0.f;
      st4(hout, (size_t)wid*32 + l2, o);
    } else {
      const float2 bv = ((const float2*)bias)[l2];
      o[0] = fmaf(acc[0], inv, bv.x);
      o[1] = fmaf(acc[1], inv, bv.y);
      o[0] = (o[0]>0.f)? o[0] : 0.f;
      o[1] = (o[1]>0.f)? o[1] : 0.f;
      sth2(hout, (size_t)wid*32 + l2, make_float2(o[0], o[1]));
    }
  }
}

// ---------------- pipeline ----------------
template<typename TM, typename TO>
static void run_pipeline(void* const* d_in, int ei_idx, int pbase, int n, int E,
                         void* d_out, int out_size, void* d_ws, size_t ws_size,
                         hipStream_t stream){
  const void* x = d_in[0];
  const int* ei = (const int*)d_in[ei_idx];
  float* out = (float*)d_out;           // fp32 output
  int Etot = E + n;

  char* p = (char*)d_ws;
  auto alloc = [&](size_t bytes)->char* {
    char* r = p; p += (bytes + 255) & ~(size_t)255; return r;
  };
  int*   flag   = (int*)  alloc(256);
  int*   eflag  = (int*)  alloc(256);
  int*   counts = (int*)  alloc((size_t)n * 4);
  float* als    = (float*)alloc((size_t)n * 16);
  float* ald    = (float*)alloc((size_t)n * 16);
  float* prm    = (float*)alloc(48000 * 4);
  // concatenated split-fp16 fragment-major W copies
  // [wh0 16384][wl0 16384][wh1 16384][wl1 16384][wh2 8192][wl2 8192][whc 3072][wlc 3072]
  uint16_t* whl = (uint16_t*)alloc(88064 * 2);

  // csr/offs/rank/bsums in d_out (fp32 out: 16 MB; dead until classifier)
  size_t csr_b  = ((size_t)Etot * 4 + 255) & ~(size_t)255;
  size_t offs_b = ((size_t)(n + 1) * 4 + 255) & ~(size_t)255;
  size_t rank_b = ((size_t)Etot * 4 + 255) & ~(size_t)255;
  size_t out_bytes = (size_t)out_size * 4;
  int *csr, *offs, *rank, *bsums;
  if (csr_b + offs_b + rank_b + 4096 <= out_bytes){
    char* q = (char*)d_out;
    csr   = (int*)q;
    offs  = (int*)(q + csr_b);
    rank  = (int*)(q + csr_b + offs_b);
    bsums = (int*)(q + csr_b + offs_b + rank_b);
  } else {
    csr   = (int*)alloc((size_t)Etot * 4);
    offs  = (int*)alloc((size_t)(n + 1) * 4);
    rank  = (int*)alloc((size_t)Etot * 4);
    bsums = (int*)alloc(4096);
  }
  TM* bufMid = (TM*)alloc((size_t)n * 128 * sizeof(TM));
  TO* bufOut = (TO*)alloc((size_t)n * 128 * sizeof(TO));

  PP pp;
  static const int cnts[14] = {16384,128,128,128, 16384,128,128,128, 8192,64,64,64, 2560,40};
  int off = 0;
  for (int i = 0; i < 14; i++){
    pp.src[i] = d_in[pbase + i];
    pp.cnt[i] = cnts[i];
    pp.off[i] = off;
    off += cnts[i];
  }
  const float* W0  = prm + pp.off[0];
  const float* as0 = prm + pp.off[1];
  const float* ad0 = prm + pp.off[2];
  const float* b0  = prm + pp.off[3];
  const float* as1 = prm + pp.off[5];
  const float* ad1 = prm + pp.off[6];
  const float* b1  = prm + pp.off[7];
  const float* as2 = prm + pp.off[9];
  const float* ad2 = prm + pp.off[10];
  const float* b2  = prm + pp.off[11];
  const float* bc  = prm + pp.off[13];

  uint16_t* wh0 = whl;
  uint16_t* wl0 = whl + 16384;
  uint16_t* wh1 = whl + 32768;
  uint16_t* wl1 = whl + 49152;
  uint16_t* wh2 = whl + 65536;
  uint16_t* wl2 = whl + 73728;
  uint16_t* whc = whl + 81920;
  uint16_t* wlc = whl + 84992;

  hipMemsetAsync(counts, 0, (size_t)n * 4, stream);

  detect2_kernel<<<1, 128, 0, stream>>>((const uint32_t*)x, (const uint32_t*)ei, flag, eflag);
  cvt_params_kernel<<<14, 256, 0, stream>>>(pp, prm, flag);

  WF wf;
  wf.src[0]=pp.off[0]; wf.src[1]=pp.off[4]; wf.src[2]=pp.off[8]; wf.src[3]=pp.off[12];
  wf.dst[0]=0; wf.dst[1]=32768; wf.dst[2]=65536; wf.dst[3]=81920;
  wf.cnt[0]=16384; wf.cnt[1]=16384; wf.cnt[2]=8192; wf.cnt[3]=3072;
  wf.K[0]=128; wf.K[1]=128; wf.K[2]=128; wf.K[3]=64;
  wf.Ms[0]=128; wf.Ms[1]=128; wf.Ms[2]=64; wf.Ms[3]=40;
  wf.Mp[0]=128; wf.Mp[1]=128; wf.Mp[2]=64; wf.Mp[3]=48;
  wf.blk0[0]=0; wf.blk0[1]=8; wf.blk0[2]=16; wf.blk0[3]=20; wf.blk0[4]=22;
  wfrag4_kernel<<<22, 256, 0, stream>>>(prm, whl, wf);

  count_kernel<<<(Etot + 255)/256, 256, 0, stream>>>(ei, eflag, counts, rank, E, n);
  int nb = (n + SCAN_CHUNK - 1) / SCAN_CHUNK;
  scan1_kernel<<<nb, SCAN_BS, 0, stream>>>(counts, offs, bsums, n);
  scan2_kernel<<<1, 1024, 0, stream>>>(bsums, nb);
  scan3_kernel<<<(n + 1 + 255)/256, 256, 0, stream>>>(offs, bsums, n, Etot);
  fill_kernel<<<(Etot + 255)/256, 256, 0, stream>>>(ei, eflag, offs, rank, csr, E, n);

  int gg   = (n + 127) / 128;    // MFMA gemms: 128 rows/block
  int log_grid = (n*4 + 255) / 256;
  int agg_grid = (n + 3) / 4;

  // layer 0: x -> bufMid -> bufOut   (x dtype runtime-detected; expect fp32)
  gemm_mfma<128,128,true,TO,TM><<<gg, 256, 0, stream>>>(x, wh0, wl0, bufMid, n, flag);
  logits_kernel<128,32,TM><<<log_grid, 256, 0, stream>>>(bufMid, as0, ad0, als, ald, n);
  aggregate_kernel<128,TM,TO><<<agg_grid, 256, 0, stream>>>(bufMid, als, ald, offs, csr, b0, bufOut, n);

  // layer 1
  gemm_mfma<128,128,false,TO,TM><<<gg, 256, 0, stream>>>(bufOut, wh1, wl1, bufMid, n, flag);
  logits_kernel<128,32,TM><<<log_grid, 256, 0, stream>>>(bufMid, as1, ad1, als, ald, n);
  aggregate_kernel<128,TM,TO><<<agg_grid, 256, 0, stream>>>(bufMid, als, ald, offs, csr, b1, bufOut, n);

  // layer 2 (outd=64)
  gemm_mfma<128,64,false,TO,TM><<<gg, 256, 0, stream>>>(bufOut, wh2, wl2, bufMid, n, flag);
  logits_kernel<64,16,TM><<<log_grid, 256, 0, stream>>>(bufMid, as2, ad2, als, ald, n);
  aggregate_kernel<64,TM,TO><<<agg_grid, 256, 0, stream>>>(bufMid, als, ald, offs, csr, b2, bufOut, n);

  // classifier (MFMA): fp32 writes, fully overwrites d_out
  gemm_cls<TO><<<gg, 256, 0, stream>>>(bufOut, whc, wlc, bc, out, n);
}

// ---------------- launcher ----------------
extern "C" void kernel_launch(void* const* d_in, const int* in_sizes, int n_in,
                              void* d_out, int out_size, void* d_ws, size_t ws_size,
                              hipStream_t stream) {
  int n = in_sizes[0] / 128;

  int ei_idx, pbase;
  if (n_in >= 2 && in_sizes[1] > 1000000) { ei_idx = 1;        pbase = 2; }   // dict order
  else                                    { ei_idx = n_in - 1; pbase = 1; }   // signature order
  int E = in_sizes[ei_idx] / 2;

  size_t base = 512
              + (((size_t)n*4  + 255) & ~(size_t)255)
              + 2*(((size_t)n*16 + 255) & ~(size_t)255)
              + ((48000*4 + 255) & ~(size_t)255)
              + ((88064*2 + 255) & ~(size_t)255)       // whl
              + 65536
              + 3*(((size_t)(E + n)*4 + 255) & ~(size_t)255);  // csr/offs/rank fallback
  size_t f32buf  = ((size_t)n*128*4 + 255) & ~(size_t)255;
  size_t h16buf  = ((size_t)n*128*2 + 255) & ~(size_t)255;

  if (ws_size >= base + f32buf + h16buf)       // tier 1: fp16 gather buf, fp32 h
    run_pipeline<h16, float>(d_in, ei_idx, pbase, n, E, d_out, out_size, d_ws, ws_size, stream);
  else                                         // tier 2: all 16-bit
    run_pipeline<h16, uint16_t>(d_in, ei_idx, pbase, n, E, d_out, out_size, d_ws, ws_size, stream);
}

// Round 12
// 539.935 us; speedup vs baseline: 1.2573x; 1.0295x over previous
//
#include <hip/hip_runtime.h>
#include <hip/hip_bf16.h>
#include <hip/hip_fp16.h>
#include <stdint.h>

typedef __hip_bfloat16 bf16;
typedef _Float16 f16;
typedef __attribute__((ext_vector_type(8))) _Float16 f16x8;
typedef __attribute__((ext_vector_type(4))) _Float16 f16x4;
typedef __attribute__((ext_vector_type(2))) _Float16 f16x2;
typedef __attribute__((ext_vector_type(4))) float    f32x4;

__device__ __forceinline__ float us2f(uint16_t u){
  union { uint32_t i; float f; } v; v.i = ((uint32_t)u) << 16; return v.f;
}
__device__ __forceinline__ float bflo(uint32_t u){
  union { uint32_t i; float f; } v; v.i = u << 16; return v.f;
}
__device__ __forceinline__ float bfhi(uint32_t u){
  union { uint32_t i; float f; } v; v.i = u & 0xffff0000u; return v.f;
}
__device__ __forceinline__ uint16_t f2u16(float f){
  union { bf16 b; uint16_t u; } v; v.b = __float2bfloat16(f); return v.u;
}
// fp16 storage type (distinct from uint16_t=bf16 for overload resolution)
struct h16 { uint16_t v; };

// storage helpers: h buffers are float, bf16(uint16_t), or fp16(h16)
__device__ __forceinline__ float  ldh (const float* p, size_t i){ return p[i]; }
__device__ __forceinline__ float  ldh (const uint16_t* p, size_t i){ return us2f(p[i]); }
__device__ __forceinline__ float  ldh (const h16* p, size_t i){ return __half2float(((const __half*)p)[i]); }
__device__ __forceinline__ float2 ldh2(const float* p, size_t i){ return ((const float2*)p)[i]; }
__device__ __forceinline__ float2 ldh2(const uint16_t* p, size_t i){
  uint32_t u = ((const uint32_t*)p)[i]; return make_float2(bflo(u), bfhi(u));
}
__device__ __forceinline__ float2 ldh2(const h16* p, size_t i){
  __half2 u = ((const __half2*)p)[i];
  return make_float2(__low2float(u), __high2float(u));
}
__device__ __forceinline__ void sth (float* p, size_t i, float v){ p[i] = v; }
__device__ __forceinline__ void sth (uint16_t* p, size_t i, float v){ p[i] = f2u16(v); }
__device__ __forceinline__ void sth (h16* p, size_t i, float v){ ((__half*)p)[i] = __float2half(v); }
__device__ __forceinline__ void sth2(float* p, size_t i, float2 v){ ((float2*)p)[i] = v; }
__device__ __forceinline__ void sth2(uint16_t* p, size_t i, float2 v){
  ((uint32_t*)p)[i] = (uint32_t)f2u16(v.x) | ((uint32_t)f2u16(v.y) << 16);
}
__device__ __forceinline__ void sth2(h16* p, size_t i, float2 v){
  ((__half2*)p)[i] = __float22half2_rn(v);
}
// gather loaders for the aggregate: fp16 buffers return _Float16 (cvt fuses
// into v_fma_mix at the consuming fma); fp32/bf16 return float.
template<typename T> struct vtt { using t = float; };
template<> struct vtt<h16> { using t = f16; };

__device__ __forceinline__ void ld4(const float* p, size_t i4, float* o){
  float4 v = ((const float4*)p)[i4]; o[0]=v.x; o[1]=v.y; o[2]=v.z; o[3]=v.w;
}
__device__ __forceinline__ void ld4(const uint16_t* p, size_t i4, float* o){
  uint2 u = ((const uint2*)p)[i4];
  o[0]=bflo(u.x); o[1]=bfhi(u.x); o[2]=bflo(u.y); o[3]=bfhi(u.y);
}
__device__ __forceinline__ void ld4(const h16* p, size_t i4, f16* o){
  f16x4 v = ((const f16x4*)p)[i4];
  o[0]=v[0]; o[1]=v[1]; o[2]=v[2]; o[3]=v[3];
}
__device__ __forceinline__ void ld2v(const float* p, size_t i2, float* o){
  float2 v = ((const float2*)p)[i2]; o[0]=v.x; o[1]=v.y;
}
__device__ __forceinline__ void ld2v(const uint16_t* p, size_t i2, float* o){
  uint32_t u = ((const uint32_t*)p)[i2]; o[0]=bflo(u); o[1]=bfhi(u);
}
__device__ __forceinline__ void ld2v(const h16* p, size_t i2, f16* o){
  f16x2 v = ((const f16x2*)p)[i2]; o[0]=v[0]; o[1]=v[1];
}
__device__ __forceinline__ void st4(float* p, size_t i4, const float* o){
  ((float4*)p)[i4] = make_float4(o[0],o[1],o[2],o[3]);
}
__device__ __forceinline__ void st4(uint16_t* p, size_t i4, const float* o){
  uint2 u;
  u.x = (uint32_t)f2u16(o[0]) | ((uint32_t)f2u16(o[1]) << 16);
  u.y = (uint32_t)f2u16(o[2]) | ((uint32_t)f2u16(o[3]) << 16);
  ((uint2*)p)[i4] = u;
}
__device__ __forceinline__ void st4(h16* p, size_t i4, const float* o){
  ((__half2*)p)[i4*2]   = __float22half2_rn(make_float2(o[0],o[1]));
  ((__half2*)p)[i4*2+1] = __float22half2_rn(make_float2(o[2],o[3]));
}
// 8-wide consecutive loaders (32B-aligned base), for MFMA A-frags
__device__ __forceinline__ void ld8(const float* p, size_t i, float* o){
  float4 a = ((const float4*)(p+i))[0];
  float4 b = ((const float4*)(p+i))[1];
  o[0]=a.x; o[1]=a.y; o[2]=a.z; o[3]=a.w; o[4]=b.x; o[5]=b.y; o[6]=b.z; o[7]=b.w;
}
__device__ __forceinline__ void ld8(const uint16_t* p, size_t i, float* o){
  uint4 u = *(const uint4*)(p+i);
  o[0]=bflo(u.x); o[1]=bfhi(u.x); o[2]=bflo(u.y); o[3]=bfhi(u.y);
  o[4]=bflo(u.z); o[5]=bfhi(u.z); o[6]=bflo(u.w); o[7]=bfhi(u.w);
}
__device__ __forceinline__ void ld8(const h16* p, size_t i, float* o){
  const __half2* q = (const __half2*)(p+i);
  #pragma unroll
  for (int j=0;j<4;j++){ __half2 u=q[j]; o[2*j]=__low2float(u); o[2*j+1]=__high2float(u); }
}

// ---------------- dtype detections (merged) ----------------
__global__ void detect2_kernel(const uint32_t* __restrict__ x, const uint32_t* __restrict__ ei,
                               int* __restrict__ flag, int* __restrict__ eflag){
  int t = threadIdx.x;
  if (t < 64){
    uint32_t w = x[t];
    uint32_t e = (w >> 7) & 0xffu;
    bool looks_bf16 = (e >= 118 && e <= 134);
    unsigned long long m = __ballot(looks_bf16);
    if (t == 0) flag[0] = (__popcll(m) >= 32) ? 0 : 1;   // 1 = fp32 inputs
  } else {
    int lane = t - 64;
    uint32_t w = ei[lane];
    bool ok = (lane & 1) ? (w == 0u) : true;
    unsigned long long m = __ballot(ok);
    if (lane == 0) eflag[0] = (__popcll(m) == 64) ? 1 : 0;  // 1 = int64 edges
  }
}

// ---------------- params -> canonical fp32 copies ----------------
struct PP {
  const void* src[14];
  int off[14];
  int cnt[14];
};

__global__ void cvt_params_kernel(PP pp, float* __restrict__ dst, const int* __restrict__ flag){
  int b = blockIdx.x;
  int cnt = pp.cnt[b];
  float* d = dst + pp.off[b];
  if (flag[0] != 0){
    const float* s = (const float*)pp.src[b];
    for (int i = threadIdx.x; i < cnt; i += 256) d[i] = s[i];
  } else {
    const uint16_t* s = (const uint16_t*)pp.src[b];
    for (int i = threadIdx.x; i < cnt; i += 256) d[i] = us2f(s[i]);
  }
}

// ---- all W matrices -> fragment-major split-fp16 in ONE kernel ----
// Entry e = (c*CT + ct)*64 + lane; elem i: k = 32c + 8*(lane>>4) + i,
// m = 16ct + (lane&15); cols >= Ms zero-padded (classifier Wc 40->48).
struct WF {
  int src[4];   // float offset into prm
  int dst[4];   // half offset into whl (wh; wl = wh + cnt)
  int cnt[4];   // elems per split half
  int K[4], Ms[4], Mp[4];
  int blk0[5];
};

__global__ void wfrag4_kernel(const float* __restrict__ prm, uint16_t* __restrict__ whl, WF wf){
  int b = blockIdx.x;
  int w = 3;
  if (b < wf.blk0[1]) w = 0; else if (b < wf.blk0[2]) w = 1; else if (b < wf.blk0[3]) w = 2;
  int e = (b - wf.blk0[w])*256 + threadIdx.x;
  int CT = wf.Mp[w] >> 4, KC = wf.K[w] >> 5;
  if (e >= KC*CT*64) return;
  const float* W = prm + wf.src[w];
  uint16_t* wh = whl + wf.dst[w];
  uint16_t* wl = wh + wf.cnt[w];
  int Ms = wf.Ms[w];
  int l = e & 63, t = e >> 6;
  int ct = t % CT, c = t / CT;
  int kbase = c*32 + (l>>4)*8;
  int m = ct*16 + (l&15);
  #pragma unroll
  for (int i=0;i<8;i++){
    float v = (m < Ms) ? W[(size_t)(kbase+i)*Ms + m] : 0.f;
    f16 h = (f16)v;
    f16 r = (f16)(v - (float)h);
    union { f16 f; uint16_t u; } ch, cr; ch.f = h; cr.f = r;
    wh[(size_t)e*8 + i] = ch.u;
    wl[(size_t)e*8 + i] = cr.u;
  }
}

// ---------------- CSR build ----------------
// rank trick: the ONLY atomic pass. rank[i] = old count (coalesced write);
// fill then needs no atomic at all.
__global__ void count_kernel(const int* __restrict__ ei, const int* __restrict__ eflag,
                             int* __restrict__ counts, int* __restrict__ rank,
                             int E, int n){
  int i = blockIdx.x * 256 + threadIdx.x;
  if (i >= E + n) return;
  int d;
  if (i < E) d = eflag[0] ? ei[2*(size_t)E + 2*(size_t)i] : ei[(size_t)E + i];
  else       d = i - E;
  rank[i] = atomicAdd(&counts[d], 1);
}

#define SCAN_BS 256
#define SCAN_CHUNK 1024

__global__ void scan1_kernel(const int* __restrict__ counts, int* __restrict__ offs,
                             int* __restrict__ bsums, int n){
  __shared__ int sdata[SCAN_BS];
  int b = blockIdx.x, t = threadIdx.x;
  int base = b * SCAN_CHUNK + t * 4;
  int v[4]; int s = 0;
  #pragma unroll
  for (int j=0;j<4;j++){ int idx = base+j; v[j] = (idx<n)? counts[idx] : 0; s += v[j]; }
  sdata[t] = s;
  __syncthreads();
  for (int off=1; off<SCAN_BS; off<<=1){
    int x = (t>=off)? sdata[t-off] : 0;
    __syncthreads();
    sdata[t] += x;
    __syncthreads();
  }
  int run = sdata[t] - s;
  #pragma unroll
  for (int j=0;j<4;j++){ int idx = base+j; if (idx<n) offs[idx] = run; run += v[j]; }
  if (t == SCAN_BS-1) bsums[b] = sdata[t];
}

__global__ void scan2_kernel(int* __restrict__ bsums, int nb){
  __shared__ int sdata[1024];
  int t = threadIdx.x;
  int v = (t<nb)? bsums[t] : 0;
  sdata[t] = v;
  __syncthreads();
  for (int off=1; off<1024; off<<=1){
    int x = (t>=off)? sdata[t-off] : 0;
    __syncthreads();
    sdata[t] += x;
    __syncthreads();
  }
  if (t<nb) bsums[t] = sdata[t] - v;
}

__global__ void scan3_kernel(int* __restrict__ offs, const int* __restrict__ bsums,
                             int n, int total){
  int i = blockIdx.x * 256 + threadIdx.x;
  if (i < n) offs[i] += bsums[i / SCAN_CHUNK];
  if (i == n) offs[n] = total;
}

// atomic-free fill: coalesced ei+rank reads, L2-resident offs gather, scatter store
__global__ void fill_kernel(const int* __restrict__ ei, const int* __restrict__ eflag,
                            const int* __restrict__ offs, const int* __restrict__ rank,
                            int* __restrict__ csr, int E, int n){
  int i = blockIdx.x * 256 + threadIdx.x;
  if (i >= E + n) return;
  int s, d;
  if (i < E){
    if (eflag[0]){ s = ei[2*(size_t)i]; d = ei[2*(size_t)E + 2*(size_t)i]; }
    else         { s = ei[i];           d = ei[(size_t)E + i]; }
  } else { s = i - E; d = i - E; }
  csr[offs[d] + rank[i]] = s;
}

// ---- GEMM: split-fp16 MFMA, barrier-free, LDS-free, FUSED LOGITS ----
// acc += Ah*Wh + Al*Wh + Ah*Wl (3 MFMA, fp32 accumulate), residual ~eps^2.
// C/D layout per m89: col=lane&15, row=(lane>>4)*4+reg.
// Epilogue computes als/ald per row from unrounded acc: 16-lane butterfly
// reduce per head (head = col>>5 for M=128, col>>4 for M=64), replacing the
// separate logits_kernel (saves a full bufMid re-read + launch per layer).
template<int K, int M, bool DET, typename TA, typename TC>
__global__ __launch_bounds__(256) void gemm_mfma(const void* __restrict__ Ap,
    const uint16_t* __restrict__ whb, const uint16_t* __restrict__ wlb,
    TC* __restrict__ C, const float* __restrict__ asrc, const float* __restrict__ adst,
    float* __restrict__ als, float* __restrict__ ald,
    int n, const int* __restrict__ flag){
  constexpr int CT = M/16;     // col tiles
  constexpr int KC = K/32;     // k chunks
  constexpr int RT = 2;        // row tiles per wave (32 rows)
  int tid = threadIdx.x;
  int wv  = tid >> 6, l = tid & 63;
  int lr  = l & 15, kg = l >> 4;
  int r0  = blockIdx.x*(64*RT) + wv*(16*RT);

  bool f32 = DET ? (flag[0] != 0) : false;
  const uint16_t* Au = (const uint16_t*)Ap;
  const float*    Af = (const float*)Ap;
  const TA*       At = (const TA*)Ap;
  const f16x8* Wh = (const f16x8*)whb;
  const f16x8* Wl = (const f16x8*)wlb;

  f32x4 acc[RT][CT];
  #pragma unroll
  for (int rt=0;rt<RT;rt++)
    #pragma unroll
    for (int ct=0;ct<CT;ct++) acc[rt][ct] = (f32x4){0.f,0.f,0.f,0.f};

  for (int c=0; c<KC; c++){
    f16x8 ah[RT], al[RT];
    #pragma unroll
    for (int rt=0;rt<RT;rt++){
      int arow = r0 + rt*16 + lr;
      if (arow > n-1) arow = n-1;
      size_t idx = (size_t)arow*K + c*32 + kg*8;
      float av[8];
      if (DET){
        if (f32) ld8(Af, idx, av);
        else     ld8(Au, idx, av);
      } else {
        ld8(At, idx, av);
      }
      #pragma unroll
      for (int i=0;i<8;i++){
        f16 h = (f16)av[i];
        ah[rt][i] = h;
        al[rt][i] = (f16)(av[i] - (float)h);
      }
    }
    #pragma unroll
    for (int ct=0;ct<CT;ct++){
      f16x8 bh = Wh[(size_t)(c*CT + ct)*64 + l];
      f16x8 bl = Wl[(size_t)(c*CT + ct)*64 + l];
      #pragma unroll
      for (int rt=0;rt<RT;rt++){
        acc[rt][ct] = __builtin_amdgcn_mfma_f32_16x16x32_f16(ah[rt], bh, acc[rt][ct], 0, 0, 0);
        acc[rt][ct] = __builtin_amdgcn_mfma_f32_16x16x32_f16(al[rt], bh, acc[rt][ct], 0, 0, 0);
        acc[rt][ct] = __builtin_amdgcn_mfma_f32_16x16x32_f16(ah[rt], bl, acc[rt][ct], 0, 0, 0);
      }
    }
  }

  // attention vectors for this lane's columns
  float avs[CT], avd[CT];
  #pragma unroll
  for (int ct=0;ct<CT;ct++){
    avs[ct] = asrc[ct*16 + lr];
    avd[ct] = adst[ct*16 + lr];
  }

  #pragma unroll
  for (int rt=0;rt<RT;rt++){
    #pragma unroll
    for (int r=0;r<4;r++){
      int orow = r0 + rt*16 + kg*4 + r;
      float ps[4] = {0.f,0.f,0.f,0.f};
      float pd[4] = {0.f,0.f,0.f,0.f};
      #pragma unroll
      for (int ct=0;ct<CT;ct++){
        constexpr int SH = (M == 128) ? 1 : 0;   // head = ct>>1 (M=128) or ct
        int h = ct >> SH;
        ps[h] = fmaf(acc[rt][ct][r], avs[ct], ps[h]);
        pd[h] = fmaf(acc[rt][ct][r], avd[ct], pd[h]);
      }
      #pragma unroll
      for (int off=1; off<16; off<<=1){
        #pragma unroll
        for (int h=0;h<4;h++){
          ps[h] += __shfl_xor(ps[h], off);
          pd[h] += __shfl_xor(pd[h], off);
        }
      }
      if (orow < n){
        #pragma unroll
        for (int ct=0;ct<CT;ct++)
          sth(C, (size_t)orow*M + ct*16 + lr, acc[rt][ct][r]);
        if (lr < 4)       als[(size_t)orow*4 + lr]      = ps[lr];
        else if (lr < 8)  ald[(size_t)orow*4 + (lr-4)]  = pd[lr-4];
      }
    }
  }
}

// ---- classifier as split-fp16 MFMA: out[n,40] = h[n,64] @ Wc + bc ----
// Wc padded to 64x48 fragment-major (wfrag4 w=3). K=64 -> KC=2, CT=3.
// fp32 bias epilogue, cols >= 40 masked. No relu.
template<typename TA>
__global__ __launch_bounds__(256) void gemm_cls(const TA* __restrict__ A,
    const uint16_t* __restrict__ whb, const uint16_t* __restrict__ wlb,
    const float* __restrict__ bc, float* __restrict__ out, int n){
  constexpr int CT = 3, KC = 2, RT = 2;
  int tid = threadIdx.x;
  int wv  = tid >> 6, l = tid & 63;
  int lr  = l & 15, kg = l >> 4;
  int r0  = blockIdx.x*128 + wv*32;
  const f16x8* Wh = (const f16x8*)whb;
  const f16x8* Wl = (const f16x8*)wlb;

  f32x4 acc[RT][CT];
  #pragma unroll
  for (int rt=0;rt<RT;rt++)
    #pragma unroll
    for (int ct=0;ct<CT;ct++) acc[rt][ct] = (f32x4){0.f,0.f,0.f,0.f};

  for (int c=0; c<KC; c++){
    f16x8 ah[RT], al[RT];
    #pragma unroll
    for (int rt=0;rt<RT;rt++){
      int arow = r0 + rt*16 + lr;
      if (arow > n-1) arow = n-1;
      size_t idx = (size_t)arow*64 + c*32 + kg*8;
      float av[8];
      ld8(A, idx, av);
      #pragma unroll
      for (int i=0;i<8;i++){
        f16 h = (f16)av[i];
        ah[rt][i] = h;
        al[rt][i] = (f16)(av[i] - (float)h);
      }
    }
    #pragma unroll
    for (int ct=0;ct<CT;ct++){
      f16x8 bh = Wh[(size_t)(c*CT + ct)*64 + l];
      f16x8 bl = Wl[(size_t)(c*CT + ct)*64 + l];
      #pragma unroll
      for (int rt=0;rt<RT;rt++){
        acc[rt][ct] = __builtin_amdgcn_mfma_f32_16x16x32_f16(ah[rt], bh, acc[rt][ct], 0, 0, 0);
        acc[rt][ct] = __builtin_amdgcn_mfma_f32_16x16x32_f16(al[rt], bh, acc[rt][ct], 0, 0, 0);
        acc[rt][ct] = __builtin_amdgcn_mfma_f32_16x16x32_f16(ah[rt], bl, acc[rt][ct], 0, 0, 0);
      }
    }
  }

  #pragma unroll
  for (int rt=0;rt<RT;rt++){
    #pragma unroll
    for (int r=0;r<4;r++){
      int orow = r0 + rt*16 + kg*4 + r;
      if (orow < n){
        #pragma unroll
        for (int ct=0;ct<CT;ct++){
          int col = ct*16 + lr;
          if (col < 40)
            out[(size_t)orow*40 + col] = acc[rt][ct][r] + bc[col];
        }
      }
    }
  }
}

// ---------------- aggregation: one wave per destination node ----------------
// SINGLE PASS (no segment-max; |e| << 88 so exp is safe). Fully predicated:
// 4 row-gathers per half-wave every iteration, OOB slots clamp with ex=0.
// fp16 gathers stay _Float16 until the fma -> v_fma_mix_f32.
template<int OUTD, typename TIN, typename TOUT>
__global__ __launch_bounds__(256) void aggregate_kernel(const TIN* __restrict__ hW,
            const float* __restrict__ als, const float* __restrict__ ald,
            const int* __restrict__ offs, const int* __restrict__ csr,
            const float* __restrict__ bias, TOUT* __restrict__ hout, int n){
  constexpr int VEC = OUTD / 32;          // 4 (OUTD=128) or 2 (OUTD=64)
  using VT = typename vtt<TIN>::t;
  int wid = (blockIdx.x * 256 + threadIdx.x) >> 6;   // node
  if (wid >= n) return;
  int lane = threadIdx.x & 63;
  int half = lane >> 5;
  int l2   = lane & 31;
  int h    = l2 >> 3;       // head for this lane's dims (both OUTD)
  int beg = offs[wid], end = offs[wid+1];
  float adh = ald[(size_t)wid*4 + h];

  float acc[VEC];
  #pragma unroll
  for (int k=0;k<VEC;k++) acc[k] = 0.f;
  float den = 0.f;

  int last = end - 1;
  for (int j = beg + half; j < end; j += 8){
    int j1 = j+2, j2 = j+4, j3 = j+6;
    bool p1 = j1 < end, p2 = j2 < end, p3 = j3 < end;
    int s0 = csr[j];
    int s1 = csr[p1 ? j1 : last];
    int s2 = csr[p2 ? j2 : last];
    int s3 = csr[p3 ? j3 : last];
    VT v0[VEC], v1[VEC], v2[VEC], v3[VEC];
    if constexpr (VEC == 4){
      ld4(hW, (size_t)s0*32 + l2, v0);
      ld4(hW, (size_t)s1*32 + l2, v1);
      ld4(hW, (size_t)s2*32 + l2, v2);
      ld4(hW, (size_t)s3*32 + l2, v3);
    } else {
      ld2v(hW, (size_t)s0*32 + l2, v0);
      ld2v(hW, (size_t)s1*32 + l2, v1);
      ld2v(hW, (size_t)s2*32 + l2, v2);
      ld2v(hW, (size_t)s3*32 + l2, v3);
    }
    float e0 = als[(size_t)s0*4 + h] + adh;
    float e1 = als[(size_t)s1*4 + h] + adh;
    float e2 = als[(size_t)s2*4 + h] + adh;
    float e3 = als[(size_t)s3*4 + h] + adh;
    e0 = (e0>0.f)? e0 : 0.2f*e0;
    e1 = (e1>0.f)? e1 : 0.2f*e1;
    e2 = (e2>0.f)? e2 : 0.2f*e2;
    e3 = (e3>0.f)? e3 : 0.2f*e3;
    float ex0 = __expf(e0);
    float ex1 = p1 ? __expf(e1) : 0.f;
    float ex2 = p2 ? __expf(e2) : 0.f;
    float ex3 = p3 ? __expf(e3) : 0.f;
    den += (ex0 + ex1) + (ex2 + ex3);
    #pragma unroll
    for (int k=0;k<VEC;k++){
      acc[k] = fmaf(ex0, (float)v0[k], acc[k]);
      acc[k] = fmaf(ex1, (float)v1[k], acc[k]);
      acc[k] = fmaf(ex2, (float)v2[k], acc[k]);
      acc[k] = fmaf(ex3, (float)v3[k], acc[k]);
    }
  }

  // combine the two halves
  den += __shfl_xor(den, 32);
  #pragma unroll
  for (int k=0;k<VEC;k++) acc[k] += __shfl_xor(acc[k], 32);

  if (half == 0){
    float inv = 1.f / (den + 1e-16f);
    float o[VEC];
    if constexpr (VEC == 4){
      const float4 bv = ((const float4*)bias)[l2];
      o[0] = fmaf(acc[0], inv, bv.x);
      o[1] = fmaf(acc[1], inv, bv.y);
      o[2] = fmaf(acc[2], inv, bv.z);
      o[3] = fmaf(acc[3], inv, bv.w);
      #pragma unroll
      for (int k=0;k<4;k++) o[k] = (o[k]>0.f)? o[k] : 0.f;
      st4(hout, (size_t)wid*32 + l2, o);
    } else {
      const float2 bv = ((const float2*)bias)[l2];
      o[0] = fmaf(acc[0], inv, bv.x);
      o[1] = fmaf(acc[1], inv, bv.y);
      o[0] = (o[0]>0.f)? o[0] : 0.f;
      o[1] = (o[1]>0.f)? o[1] : 0.f;
      sth2(hout, (size_t)wid*32 + l2, make_float2(o[0], o[1]));
    }
  }
}

// ---------------- pipeline ----------------
template<typename TM, typename TO>
static void run_pipeline(void* const* d_in, int ei_idx, int pbase, int n, int E,
                         void* d_out, int out_size, void* d_ws, size_t ws_size,
                         hipStream_t stream){
  const void* x = d_in[0];
  const int* ei = (const int*)d_in[ei_idx];
  float* out = (float*)d_out;           // fp32 output
  int Etot = E + n;

  char* p = (char*)d_ws;
  auto alloc = [&](size_t bytes)->char* {
    char* r = p; p += (bytes + 255) & ~(size_t)255; return r;
  };
  int*   flag   = (int*)  alloc(256);
  int*   eflag  = (int*)  alloc(256);
  int*   counts = (int*)  alloc((size_t)n * 4);
  float* als    = (float*)alloc((size_t)n * 16);
  float* ald    = (float*)alloc((size_t)n * 16);
  float* prm    = (float*)alloc(48000 * 4);
  // concatenated split-fp16 fragment-major W copies
  // [wh0 16384][wl0 16384][wh1 16384][wl1 16384][wh2 8192][wl2 8192][whc 3072][wlc 3072]
  uint16_t* whl = (uint16_t*)alloc(88064 * 2);

  // csr/offs/rank/bsums in d_out (fp32 out: 16 MB; dead until classifier)
  size_t csr_b  = ((size_t)Etot * 4 + 255) & ~(size_t)255;
  size_t offs_b = ((size_t)(n + 1) * 4 + 255) & ~(size_t)255;
  size_t rank_b = ((size_t)Etot * 4 + 255) & ~(size_t)255;
  size_t out_bytes = (size_t)out_size * 4;
  int *csr, *offs, *rank, *bsums;
  if (csr_b + offs_b + rank_b + 4096 <= out_bytes){
    char* q = (char*)d_out;
    csr   = (int*)q;
    offs  = (int*)(q + csr_b);
    rank  = (int*)(q + csr_b + offs_b);
    bsums = (int*)(q + csr_b + offs_b + rank_b);
  } else {
    csr   = (int*)alloc((size_t)Etot * 4);
    offs  = (int*)alloc((size_t)(n + 1) * 4);
    rank  = (int*)alloc((size_t)Etot * 4);
    bsums = (int*)alloc(4096);
  }
  TM* bufMid = (TM*)alloc((size_t)n * 128 * sizeof(TM));
  TO* bufOut = (TO*)alloc((size_t)n * 128 * sizeof(TO));

  PP pp;
  static const int cnts[14] = {16384,128,128,128, 16384,128,128,128, 8192,64,64,64, 2560,40};
  int off = 0;
  for (int i = 0; i < 14; i++){
    pp.src[i] = d_in[pbase + i];
    pp.cnt[i] = cnts[i];
    pp.off[i] = off;
    off += cnts[i];
  }
  const float* as0 = prm + pp.off[1];
  const float* ad0 = prm + pp.off[2];
  const float* b0  = prm + pp.off[3];
  const float* as1 = prm + pp.off[5];
  const float* ad1 = prm + pp.off[6];
  const float* b1  = prm + pp.off[7];
  const float* as2 = prm + pp.off[9];
  const float* ad2 = prm + pp.off[10];
  const float* b2  = prm + pp.off[11];
  const float* bc  = prm + pp.off[13];

  uint16_t* wh0 = whl;
  uint16_t* wl0 = whl + 16384;
  uint16_t* wh1 = whl + 32768;
  uint16_t* wl1 = whl + 49152;
  uint16_t* wh2 = whl + 65536;
  uint16_t* wl2 = whl + 73728;
  uint16_t* whc = whl + 81920;
  uint16_t* wlc = whl + 84992;

  hipMemsetAsync(counts, 0, (size_t)n * 4, stream);

  detect2_kernel<<<1, 128, 0, stream>>>((const uint32_t*)x, (const uint32_t*)ei, flag, eflag);
  cvt_params_kernel<<<14, 256, 0, stream>>>(pp, prm, flag);

  WF wf;
  wf.src[0]=pp.off[0]; wf.src[1]=pp.off[4]; wf.src[2]=pp.off[8]; wf.src[3]=pp.off[12];
  wf.dst[0]=0; wf.dst[1]=32768; wf.dst[2]=65536; wf.dst[3]=81920;
  wf.cnt[0]=16384; wf.cnt[1]=16384; wf.cnt[2]=8192; wf.cnt[3]=3072;
  wf.K[0]=128; wf.K[1]=128; wf.K[2]=128; wf.K[3]=64;
  wf.Ms[0]=128; wf.Ms[1]=128; wf.Ms[2]=64; wf.Ms[3]=40;
  wf.Mp[0]=128; wf.Mp[1]=128; wf.Mp[2]=64; wf.Mp[3]=48;
  wf.blk0[0]=0; wf.blk0[1]=8; wf.blk0[2]=16; wf.blk0[3]=20; wf.blk0[4]=22;
  wfrag4_kernel<<<22, 256, 0, stream>>>(prm, whl, wf);

  count_kernel<<<(Etot + 255)/256, 256, 0, stream>>>(ei, eflag, counts, rank, E, n);
  int nb = (n + SCAN_CHUNK - 1) / SCAN_CHUNK;
  scan1_kernel<<<nb, SCAN_BS, 0, stream>>>(counts, offs, bsums, n);
  scan2_kernel<<<1, 1024, 0, stream>>>(bsums, nb);
  scan3_kernel<<<(n + 1 + 255)/256, 256, 0, stream>>>(offs, bsums, n, Etot);
  fill_kernel<<<(Etot + 255)/256, 256, 0, stream>>>(ei, eflag, offs, rank, csr, E, n);

  int gg   = (n + 127) / 128;    // MFMA gemms: 128 rows/block
  int agg_grid = (n + 3) / 4;

  // layer 0: x -> bufMid (+ fused logits) -> bufOut
  gemm_mfma<128,128,true,TO,TM><<<gg, 256, 0, stream>>>(x, wh0, wl0, bufMid, as0, ad0, als, ald, n, flag);
  aggregate_kernel<128,TM,TO><<<agg_grid, 256, 0, stream>>>(bufMid, als, ald, offs, csr, b0, bufOut, n);

  // layer 1
  gemm_mfma<128,128,false,TO,TM><<<gg, 256, 0, stream>>>(bufOut, wh1, wl1, bufMid, as1, ad1, als, ald, n, flag);
  aggregate_kernel<128,TM,TO><<<agg_grid, 256, 0, stream>>>(bufMid, als, ald, offs, csr, b1, bufOut, n);

  // layer 2 (outd=64)
  gemm_mfma<128,64,false,TO,TM><<<gg, 256, 0, stream>>>(bufOut, wh2, wl2, bufMid, as2, ad2, als, ald, n, flag);
  aggregate_kernel<64,TM,TO><<<agg_grid, 256, 0, stream>>>(bufMid, als, ald, offs, csr, b2, bufOut, n);

  // classifier (MFMA): fp32 writes, fully overwrites d_out
  gemm_cls<TO><<<gg, 256, 0, stream>>>(bufOut, whc, wlc, bc, out, n);
}

// ---------------- launcher ----------------
extern "C" void kernel_launch(void* const* d_in, const int* in_sizes, int n_in,
                              void* d_out, int out_size, void* d_ws, size_t ws_size,
                              hipStream_t stream) {
  int n = in_sizes[0] / 128;

  int ei_idx, pbase;
  if (n_in >= 2 && in_sizes[1] > 1000000) { ei_idx = 1;        pbase = 2; }   // dict order
  else                                    { ei_idx = n_in - 1; pbase = 1; }   // signature order
  int E = in_sizes[ei_idx] / 2;

  size_t base = 512
              + (((size_t)n*4  + 255) & ~(size_t)255)
              + 2*(((size_t)n*16 + 255) & ~(size_t)255)
              + ((48000*4 + 255) & ~(size_t)255)
              + ((88064*2 + 255) & ~(size_t)255)       // whl
              + 65536
              + 3*(((size_t)(E + n)*4 + 255) & ~(size_t)255);  // csr/offs/rank fallback
  size_t f32buf  = ((size_t)n*128*4 + 255) & ~(size_t)255;
  size_t h16buf  = ((size_t)n*128*2 + 255) & ~(size_t)255;

  if (ws_size >= base + f32buf + h16buf)       // tier 1: fp16 gather buf, fp32 h
    run_pipeline<h16, float>(d_in, ei_idx, pbase, n, E, d_out, out_size, d_ws, ws_size, stream);
  else                                         // tier 2: all 16-bit
    run_pipeline<h16, uint16_t>(d_in, ei_idx, pbase, n, E, d_out, out_size, d_ws, ws_size, stream);
}